// Round 10
// baseline (971.871 us; speedup 1.0000x reference)
//
#include <hip/hip_runtime.h>
#include <hip/hip_bf16.h>
#include <hip/hip_cooperative_groups.h>
#include <math.h>

namespace cg = cooperative_groups;

// Problem constants
#define BB 4
#define WW 2048
#define TOK (BB * WW)        // 8192
#define DMODEL 256
#define DINNER 512
#define DSTATE 16
#define DTRANK 16
#define DCONV 4
#define NLAYERS 2
#define CHUNKS 64
#define CLEN (WW / CHUNKS)   // 32
#define WA_ELEMS (NLAYERS * 2 * DINNER * DMODEL)   // 1048576
#define WO_ELEMS (NLAYERS * DMODEL * DINNER)       // 524288

typedef __attribute__((ext_vector_type(8))) short short8;
typedef __attribute__((ext_vector_type(4))) float floatx4;

static __device__ __forceinline__ unsigned short f2bf(float f) {
  __hip_bfloat16 b = __float2bfloat16(f);
  return *(unsigned short*)&b;
}
static __device__ __forceinline__ float bf2f(unsigned short u) {
  union { unsigned int i; float f; } x;
  x.i = ((unsigned int)u) << 16;
  return x.f;
}
static __device__ __forceinline__ void load_lds16(const void* g, void* l) {
  __builtin_amdgcn_global_load_lds(
      (const __attribute__((address_space(1))) unsigned int*)g,
      (__attribute__((address_space(3))) unsigned int*)l, 16, 0, 0);
}

// ===========================================================================
// Cooperative whole-model mega-kernel.  Grid-size agnostic: every stage is a
// grid-stride loop over its unit count; stages separated by grid.sync().
// ===========================================================================
__global__ __launch_bounds__(256, 2) void mamba_mega(
    const float* __restrict__ x, const float* __restrict__ emb_w,
    const float* __restrict__ emb_b, const float* __restrict__ in_proj_w,
    const float* __restrict__ conv_w, const float* __restrict__ conv_b,
    const float* __restrict__ x_proj_w, const float* __restrict__ dt_proj_w,
    const float* __restrict__ dt_proj_b, const float* __restrict__ A_log,
    const float* __restrict__ Dp, const float* __restrict__ out_proj_w,
    const float* __restrict__ norm_w, float* __restrict__ hout,
    float* __restrict__ wsbase) {
  cg::grid_group grid = cg::this_grid();
  __shared__ __align__(16) char smem[16384];

  const size_t M1 = 1024 * 1024;
  unsigned short* ub = (unsigned short*)wsbase;
  float* xc = wsbase + 1 * M1;
  unsigned short* zbuf = (unsigned short*)(wsbase + 5 * M1);
  unsigned short* xsb = (unsigned short*)(wsbase + 7 * M1);
  float* dbc = wsbase + 9 * M1;
  float* pf = wsbase + 9 * M1 + 524288;
  float* hf = pf + 2 * M1;
  unsigned short* ybb = (unsigned short*)(hf + 2 * M1);
  unsigned short* wA_all = (unsigned short*)(wsbase + 15 * M1 + 524288);
  unsigned short* wO_all = wA_all + (size_t)WA_ELEMS;

  int blk = blockIdx.x;
  int nblk = gridDim.x;
  int tid = threadIdx.x;
  int wave = tid >> 6;
  int lane = tid & 63;

  // ---- S0: weight cast ----
  for (int q = blk * 256 + tid; q < (WA_ELEMS + WO_ELEMS) / 4; q += nblk * 256) {
    int i = q * 4;
    if (i < WA_ELEMS) {
      float4 v = *(const float4*)&in_proj_w[i];
      ushort4 o = {f2bf(v.x), f2bf(v.y), f2bf(v.z), f2bf(v.w)};
      *(ushort4*)&wA_all[i] = o;
    } else {
      int j = i - WA_ELEMS;
      float4 v = *(const float4*)&out_proj_w[j];
      ushort4 o = {f2bf(v.x), f2bf(v.y), f2bf(v.z), f2bf(v.w)};
      *(ushort4*)&wO_all[j] = o;
    }
  }
  // ---- S0b: embed + rmsnorm(layer0) over 512 token-groups of 16 ----
  {
    int d4 = lane * 4;
    float4 w = *(const float4*)&emb_w[d4];
    float4 bq = *(const float4*)&emb_b[d4];
    float4 nv = *(const float4*)&norm_w[d4];
    for (int tg = blk; tg < 512; tg += nblk) {
#pragma unroll
      for (int i = 0; i < 4; i++) {
        int tok = tg * 16 + wave * 4 + i;
        float xv = x[tok];
        float4 e;
        e.x = xv * w.x + bq.x;
        e.y = xv * w.y + bq.y;
        e.z = xv * w.z + bq.z;
        e.w = xv * w.w + bq.w;
        *(float4*)&hout[(size_t)tok * DMODEL + d4] = e;
        float ss = e.x * e.x + e.y * e.y + e.z * e.z + e.w * e.w;
#pragma unroll
        for (int off = 32; off; off >>= 1) ss += __shfl_xor(ss, off, 64);
        float rs = rsqrtf(ss * (1.0f / 256.0f) + 1e-5f);
        ushort4 o;
        o.x = f2bf(e.x * rs * nv.x);
        o.y = f2bf(e.y * rs * nv.y);
        o.z = f2bf(e.z * rs * nv.z);
        o.w = f2bf(e.w * rs * nv.w);
        *(ushort4*)&ub[(size_t)tok * DMODEL + d4] = o;
      }
    }
  }
  grid.sync();

  for (int l = 0; l < NLAYERS; l++) {
    const unsigned short* wA = wA_all + (size_t)l * 2 * DINNER * DMODEL;
    const unsigned short* wO = wO_all + (size_t)l * DMODEL * DINNER;
    const float* cw = conv_w + (size_t)l * DINNER * DCONV;
    const float* cb = conv_b + (size_t)l * DINNER;
    const float* xw = x_proj_w + (size_t)l * 48 * DINNER;
    const float* dtw = dt_proj_w + (size_t)l * DINNER * DTRANK;
    const float* dtb = dt_proj_b + (size_t)l * DINNER;
    const float* Alog = A_log + (size_t)l * DINNER * DSTATE;
    const float* Dpl = Dp + (size_t)l * DINNER;

    // ---- S1: in_proj 128x128 MFMA (512 tiles), split epilogue ----
    for (int tile = blk; tile < 512; tile += nblk) {
      unsigned short* As = (unsigned short*)smem;
      unsigned short* Bs = As + 4096;
      int wm = (wave & 1) * 64;
      int wn = (wave >> 1) * 64;
      int m0 = (tile >> 3) * 128;
      int n0 = (tile & 7) * 128;
      int mlane = lane & 15;
      int quad = lane >> 4;
      const int K = DMODEL;
      floatx4 acc[4][4] = {};
      for (int k0 = 0; k0 < K; k0 += 32) {
#pragma unroll
        for (int i = 0; i < 2; i++) {
          int off = i * 4096 + wave * 1024 + lane * 16;
          int row = off >> 6, col = off & 63;
          load_lds16((const char*)ub + ((size_t)(m0 + row) * K + k0) * 2 + col,
                     (char*)As + i * 4096 + wave * 1024);
        }
#pragma unroll
        for (int i = 0; i < 2; i++) {
          int off = i * 4096 + wave * 1024 + lane * 16;
          int row = off >> 6, col = off & 63;
          load_lds16((const char*)wA + ((size_t)(n0 + row) * K + k0) * 2 + col,
                     (char*)Bs + i * 4096 + wave * 1024);
        }
        __syncthreads();
        short8 af[4], bf[4];
#pragma unroll
        for (int i = 0; i < 4; i++)
          af[i] = *(const short8*)((const char*)As + (wm + i * 16 + mlane) * 64 + quad * 16);
#pragma unroll
        for (int j = 0; j < 4; j++)
          bf[j] = *(const short8*)((const char*)Bs + (wn + j * 16 + mlane) * 64 + quad * 16);
#pragma unroll
        for (int i = 0; i < 4; i++)
#pragma unroll
          for (int j = 0; j < 4; j++)
            acc[i][j] = __builtin_amdgcn_mfma_f32_16x16x32_bf16(af[i], bf[j], acc[i][j], 0, 0, 0);
        __syncthreads();
      }
#pragma unroll
      for (int i = 0; i < 4; i++) {
#pragma unroll
        for (int j = 0; j < 4; j++) {
          int n = n0 + wn + j * 16 + mlane;
#pragma unroll
          for (int r = 0; r < 4; r++) {
            int m = m0 + wm + i * 16 + quad * 4 + r;
            float v = acc[i][j][r];
            if (n < DINNER) xc[(size_t)m * DINNER + n] = v;
            else zbuf[(size_t)m * DINNER + (n - DINNER)] = f2bf(v);
          }
        }
      }
    }
    grid.sync();

    // ---- S2: causal conv + SiLU (131072 thread-units) ----
    for (int idx = blk * 256 + tid; idx < 131072; idx += nblk * 256) {
      int c4 = (idx & 127) * 4;
      int rest = idx >> 7;
      int strip = rest & 255;
      int bb = rest >> 8;
      int t0 = strip * 8;
      float wch[4][4];
#pragma unroll
      for (int c = 0; c < 4; c++) {
        float4 w = *(const float4*)&cw[(c4 + c) * DCONV];
        wch[c][0] = w.x; wch[c][1] = w.y; wch[c][2] = w.z; wch[c][3] = w.w;
      }
      float4 bias = *(const float4*)&cb[c4];
      const float* xp = xc + ((size_t)bb * WW) * DINNER + c4;
      float4 xm3 = make_float4(0, 0, 0, 0), xm2 = xm3, xm1 = xm3;
      if (t0 >= 3) xm3 = *(const float4*)&xp[(size_t)(t0 - 3) * DINNER];
      if (t0 >= 2) xm2 = *(const float4*)&xp[(size_t)(t0 - 2) * DINNER];
      if (t0 >= 1) xm1 = *(const float4*)&xp[(size_t)(t0 - 1) * DINNER];
      unsigned short* op = xsb + ((size_t)bb * WW) * DINNER + c4;
#pragma unroll
      for (int t = t0; t < t0 + 8; t++) {
        float4 xcur = *(const float4*)&xp[(size_t)t * DINNER];
        float a0 = bias.x, a1 = bias.y, a2 = bias.z, a3 = bias.w;
        a0 = fmaf(xm3.x, wch[0][0], fmaf(xm2.x, wch[0][1], fmaf(xm1.x, wch[0][2], fmaf(xcur.x, wch[0][3], a0))));
        a1 = fmaf(xm3.y, wch[1][0], fmaf(xm2.y, wch[1][1], fmaf(xm1.y, wch[1][2], fmaf(xcur.y, wch[1][3], a1))));
        a2 = fmaf(xm3.z, wch[2][0], fmaf(xm2.z, wch[2][1], fmaf(xm1.z, wch[2][2], fmaf(xcur.z, wch[2][3], a2))));
        a3 = fmaf(xm3.w, wch[3][0], fmaf(xm2.w, wch[3][1], fmaf(xm1.w, wch[3][2], fmaf(xcur.w, wch[3][3], a3))));
        ushort4 o;
        o.x = f2bf(a0 / (1.f + __expf(-a0)));
        o.y = f2bf(a1 / (1.f + __expf(-a1)));
        o.z = f2bf(a2 / (1.f + __expf(-a2)));
        o.w = f2bf(a3 / (1.f + __expf(-a3)));
        *(ushort4*)&op[(size_t)t * DINNER] = o;
        xm3 = xm2; xm2 = xm1; xm1 = xcur;
      }
    }
    grid.sync();

    // ---- S3: x_proj (256 tiles of BM=32) ----
    for (int tile = blk; tile < 256; tile += nblk) {
      float* As3 = (float*)smem;          // [32 k][32 m]
      float* Bs3 = As3 + 1024;            // [32 k][64 n]
      int m0 = tile * 32;
      int tx = tid & 15;
      int ty = tid >> 4;
      const int K = DINNER, N = 48;
      float acc[2][4] = {};
      for (int k0 = 0; k0 < K; k0 += 32) {
        {
          int r = tid >> 3;
          int c = (tid & 7) * 4;
          ushort4 a = *(const ushort4*)&xsb[(size_t)(m0 + r) * K + k0 + c];
          As3[(c + 0) * 32 + r] = bf2f(a.x);
          As3[(c + 1) * 32 + r] = bf2f(a.y);
          As3[(c + 2) * 32 + r] = bf2f(a.z);
          As3[(c + 3) * 32 + r] = bf2f(a.w);
        }
        {
          int rb = tid >> 2;
          int cb = (tid & 3) * 8;
#pragma unroll
          for (int i = 0; i < 2; i++) {
            int col = cb + i * 4;
            float4 v = make_float4(0.f, 0.f, 0.f, 0.f);
            if (rb < N) v = *(const float4*)&xw[(size_t)rb * K + k0 + col];
            Bs3[(col + 0) * 64 + rb] = v.x;
            Bs3[(col + 1) * 64 + rb] = v.y;
            Bs3[(col + 2) * 64 + rb] = v.z;
            Bs3[(col + 3) * 64 + rb] = v.w;
          }
        }
        __syncthreads();
#pragma unroll
        for (int kk = 0; kk < 32; kk++) {
          float av[2];
#pragma unroll
          for (int i = 0; i < 2; i++) av[i] = As3[kk * 32 + ty * 2 + i];
          float4 b = *(const float4*)&Bs3[kk * 64 + tx * 4];
          float bv[4] = {b.x, b.y, b.z, b.w};
#pragma unroll
          for (int i = 0; i < 2; i++)
#pragma unroll
            for (int j = 0; j < 4; j++) acc[i][j] = fmaf(av[i], bv[j], acc[i][j]);
        }
        __syncthreads();
      }
      int n = tx * 4;
      if (n < N) {
#pragma unroll
        for (int i = 0; i < 2; i++) {
          int m = m0 + ty * 2 + i;
          float4 v = {acc[i][0], acc[i][1], acc[i][2], acc[i][3]};
          *(float4*)&dbc[(size_t)m * N + n] = v;
        }
      }
    }
    grid.sync();

    // ---- S4: scan phase1 (512 units), fused dt+softplus ----
    for (int u = blk; u < 512; u += nblk) {
      int dblk = u & 1;
      int bc = u >> 1;
      int c = bc & (CHUNKS - 1);
      int bb = bc >> 6;
      int d = dblk * 256 + tid;
      float A[16], wt[16];
#pragma unroll
      for (int j = 0; j < 4; j++) {
        float4 v = *(const float4*)&Alog[d * DSTATE + j * 4];
        A[4 * j + 0] = -__expf(v.x);
        A[4 * j + 1] = -__expf(v.y);
        A[4 * j + 2] = -__expf(v.z);
        A[4 * j + 3] = -__expf(v.w);
        float4 q = *(const float4*)&dtw[d * DTRANK + j * 4];
        wt[4 * j + 0] = q.x; wt[4 * j + 1] = q.y;
        wt[4 * j + 2] = q.z; wt[4 * j + 3] = q.w;
      }
      float bias = dtb[d];
      float hh[16], P[16];
#pragma unroll
      for (int s = 0; s < 16; s++) { hh[s] = 0.f; P[s] = 1.f; }
      int t0 = c * CLEN;
      const unsigned short* up_ = xsb + ((size_t)(bb * WW + t0)) * DINNER + d;
      const float* bcp = dbc + ((size_t)(bb * WW + t0)) * 48;
#pragma unroll 4
      for (int t = 0; t < CLEN; t++) {
        float uv = bf2f(up_[(size_t)t * DINNER]);
        float dt16[16], Bv[16];
#pragma unroll
        for (int j = 0; j < 4; j++) {
          float4 q = *(const float4*)&bcp[t * 48 + j * 4];
          dt16[4 * j + 0] = q.x; dt16[4 * j + 1] = q.y;
          dt16[4 * j + 2] = q.z; dt16[4 * j + 3] = q.w;
          float4 r = *(const float4*)&bcp[t * 48 + DTRANK + j * 4];
          Bv[4 * j + 0] = r.x; Bv[4 * j + 1] = r.y;
          Bv[4 * j + 2] = r.z; Bv[4 * j + 3] = r.w;
        }
        float s0 = bias;
#pragma unroll
        for (int r = 0; r < 16; r++) s0 = fmaf(dt16[r], wt[r], s0);
        float dv = fmaxf(s0, 0.f) + __logf(1.f + __expf(-fabsf(s0)));
        float du = dv * uv;
#pragma unroll
        for (int s = 0; s < 16; s++) {
          float e = __expf(dv * A[s]);
          P[s] *= e;
          hh[s] = fmaf(e, hh[s], du * Bv[s]);
        }
      }
      size_t o = ((size_t)(bb * DINNER + d) * CHUNKS + c) * DSTATE;
#pragma unroll
      for (int j = 0; j < 4; j++) {
        float4 pv = {P[4 * j], P[4 * j + 1], P[4 * j + 2], P[4 * j + 3]};
        float4 hv = {hh[4 * j], hh[4 * j + 1], hh[4 * j + 2], hh[4 * j + 3]};
        *(float4*)&pf[o + 4 * j] = pv;
        *(float4*)&hf[o + 4 * j] = hv;
      }
    }
    grid.sync();

    // ---- S5: carry combine (32768 thread-units, in-place into pf) ----
    for (int idx = blk * 256 + tid; idx < 32768; idx += nblk * 256) {
      int s = idx & 15;
      int g = idx >> 4;
      float hh = 0.f;
#pragma unroll
      for (int c = 0; c < CHUNKS; c++) {
        size_t o = ((size_t)g * CHUNKS + c) * DSTATE + s;
        float P = pf[o];
        float f = hf[o];
        pf[o] = hh;
        hh = fmaf(P, hh, f);
      }
    }
    grid.sync();

    // ---- S6: scan phase3 (512 units), seeded, gated y ----
    for (int u = blk; u < 512; u += nblk) {
      int dblk = u & 1;
      int bc = u >> 1;
      int c = bc & (CHUNKS - 1);
      int bb = bc >> 6;
      int d = dblk * 256 + tid;
      float A[16], wt[16];
#pragma unroll
      for (int j = 0; j < 4; j++) {
        float4 v = *(const float4*)&Alog[d * DSTATE + j * 4];
        A[4 * j + 0] = -__expf(v.x);
        A[4 * j + 1] = -__expf(v.y);
        A[4 * j + 2] = -__expf(v.z);
        A[4 * j + 3] = -__expf(v.w);
        float4 q = *(const float4*)&dtw[d * DTRANK + j * 4];
        wt[4 * j + 0] = q.x; wt[4 * j + 1] = q.y;
        wt[4 * j + 2] = q.z; wt[4 * j + 3] = q.w;
      }
      float bias = dtb[d];
      float Dv = Dpl[d];
      float hh[16];
      size_t o = ((size_t)(bb * DINNER + d) * CHUNKS + c) * DSTATE;
#pragma unroll
      for (int j = 0; j < 4; j++) {
        float4 hv = *(const float4*)&pf[o + 4 * j];
        hh[4 * j + 0] = hv.x; hh[4 * j + 1] = hv.y;
        hh[4 * j + 2] = hv.z; hh[4 * j + 3] = hv.w;
      }
      int t0 = c * CLEN;
      const unsigned short* up_ = xsb + ((size_t)(bb * WW + t0)) * DINNER + d;
      const float* bcp = dbc + ((size_t)(bb * WW + t0)) * 48;
      const unsigned short* zp = zbuf + ((size_t)(bb * WW + t0)) * DINNER + d;
      unsigned short* yp = ybb + ((size_t)(bb * WW + t0)) * DINNER + d;
#pragma unroll 4
      for (int t = 0; t < CLEN; t++) {
        float uv = bf2f(up_[(size_t)t * DINNER]);
        float zv = bf2f(zp[(size_t)t * DINNER]);
        float dt16[16], Bv[16], Cv[16];
#pragma unroll
        for (int j = 0; j < 4; j++) {
          float4 q = *(const float4*)&bcp[t * 48 + j * 4];
          dt16[4 * j + 0] = q.x; dt16[4 * j + 1] = q.y;
          dt16[4 * j + 2] = q.z; dt16[4 * j + 3] = q.w;
          float4 r = *(const float4*)&bcp[t * 48 + DTRANK + j * 4];
          Bv[4 * j + 0] = r.x; Bv[4 * j + 1] = r.y;
          Bv[4 * j + 2] = r.z; Bv[4 * j + 3] = r.w;
          float4 u2 = *(const float4*)&bcp[t * 48 + DTRANK + DSTATE + j * 4];
          Cv[4 * j + 0] = u2.x; Cv[4 * j + 1] = u2.y;
          Cv[4 * j + 2] = u2.z; Cv[4 * j + 3] = u2.w;
        }
        float s0 = bias;
#pragma unroll
        for (int r = 0; r < 16; r++) s0 = fmaf(dt16[r], wt[r], s0);
        float dv = fmaxf(s0, 0.f) + __logf(1.f + __expf(-fabsf(s0)));
        float du = dv * uv;
        float p = 0.f;
#pragma unroll
        for (int s = 0; s < 16; s++) {
          float e = __expf(dv * A[s]);
          hh[s] = fmaf(e, hh[s], du * Bv[s]);
          p = fmaf(hh[s], Cv[s], p);
        }
        float yv = fmaf(uv, Dv, p);
        yv *= zv / (1.f + __expf(-zv));
        yp[(size_t)t * DINNER] = f2bf(yv);
      }
    }
    grid.sync();

    // ---- S7: out_proj 128x32 MFMA + residual (512 tiles) ----
    for (int tile = blk; tile < 512; tile += nblk) {
      unsigned short* As = (unsigned short*)smem;   // 128x32
      unsigned short* Bs = As + 4096;               // 32x32
      int m0 = (tile >> 3) * 128;
      int n0 = (tile & 7) * 32;
      int mlane = lane & 15;
      int quad = lane >> 4;
      const int K = DINNER;
      floatx4 acc[2][2] = {};
      for (int k0 = 0; k0 < K; k0 += 32) {
#pragma unroll
        for (int i = 0; i < 2; i++) {
          int off = i * 4096 + wave * 1024 + lane * 16;
          int row = off >> 6, col = off & 63;
          load_lds16((const char*)ybb + ((size_t)(m0 + row) * K + k0) * 2 + col,
                     (char*)As + i * 4096 + wave * 1024);
        }
        if (wave < 2) {
          int off = wave * 1024 + lane * 16;
          int row = off >> 6, col = off & 63;
          load_lds16((const char*)wO + ((size_t)(n0 + row) * K + k0) * 2 + col,
                     (char*)Bs + wave * 1024);
        }
        __syncthreads();
        short8 af[2], bf[2];
#pragma unroll
        for (int i = 0; i < 2; i++)
          af[i] = *(const short8*)((const char*)As + (wave * 32 + i * 16 + mlane) * 64 + quad * 16);
#pragma unroll
        for (int j = 0; j < 2; j++)
          bf[j] = *(const short8*)((const char*)Bs + (j * 16 + mlane) * 64 + quad * 16);
#pragma unroll
        for (int i = 0; i < 2; i++)
#pragma unroll
          for (int j = 0; j < 2; j++)
            acc[i][j] = __builtin_amdgcn_mfma_f32_16x16x32_bf16(af[i], bf[j], acc[i][j], 0, 0, 0);
        __syncthreads();
      }
#pragma unroll
      for (int i = 0; i < 2; i++) {
#pragma unroll
        for (int j = 0; j < 2; j++) {
          int n = n0 + j * 16 + mlane;
#pragma unroll
          for (int r = 0; r < 4; r++) {
            int m = m0 + wave * 32 + i * 16 + quad * 4 + r;
            float* p = &hout[(size_t)m * DMODEL + n];
            *p = acc[i][j][r] + *p;
          }
        }
      }
    }

    // ---- S8: rmsnorm for layer 1 input ----
    if (l == 0) {
      grid.sync();
      int d4 = lane * 4;
      float4 nv = *(const float4*)&norm_w[DMODEL + d4];
      for (int tg = blk; tg < 512; tg += nblk) {
#pragma unroll
        for (int i = 0; i < 4; i++) {
          int tok = tg * 16 + wave * 4 + i;
          float4 v = *(const float4*)&hout[(size_t)tok * DMODEL + d4];
          float ss = v.x * v.x + v.y * v.y + v.z * v.z + v.w * v.w;
#pragma unroll
          for (int off = 32; off; off >>= 1) ss += __shfl_xor(ss, off, 64);
          float rs = rsqrtf(ss * (1.0f / 256.0f) + 1e-5f);
          ushort4 o;
          o.x = f2bf(v.x * rs * nv.x);
          o.y = f2bf(v.y * rs * nv.y);
          o.z = f2bf(v.z * rs * nv.z);
          o.w = f2bf(v.w * rs * nv.w);
          *(ushort4*)&ub[(size_t)tok * DMODEL + d4] = o;
        }
      }
      grid.sync();
    }
  }
}

// ===========================================================================
// FALLBACK PATH: Round-8 multi-kernel pipeline (known-good, 349.9 us)
// ===========================================================================
__global__ __launch_bounds__(256) void embed_rms_kernel(
    const float* __restrict__ x, const float* __restrict__ ew,
    const float* __restrict__ eb, const float* __restrict__ nw,
    float* __restrict__ h, unsigned short* __restrict__ ub) {
  int wave = threadIdx.x >> 6;
  int lane = threadIdx.x & 63;
  int tok = blockIdx.x * 4 + wave;
  int d4 = lane * 4;
  float xv = x[tok];
  float4 w = *(const float4*)&ew[d4];
  float4 b = *(const float4*)&eb[d4];
  float4 e;
  e.x = xv * w.x + b.x;
  e.y = xv * w.y + b.y;
  e.z = xv * w.z + b.z;
  e.w = xv * w.w + b.w;
  *(float4*)&h[(size_t)tok * DMODEL + d4] = e;
  float ss = e.x * e.x + e.y * e.y + e.z * e.z + e.w * e.w;
#pragma unroll
  for (int off = 32; off; off >>= 1) ss += __shfl_xor(ss, off, 64);
  float rs = rsqrtf(ss * (1.0f / 256.0f) + 1e-5f);
  float4 nv = *(const float4*)&nw[d4];
  ushort4 o;
  o.x = f2bf(e.x * rs * nv.x);
  o.y = f2bf(e.y * rs * nv.y);
  o.z = f2bf(e.z * rs * nv.z);
  o.w = f2bf(e.w * rs * nv.w);
  *(ushort4*)&ub[(size_t)tok * DMODEL + d4] = o;
}

__global__ __launch_bounds__(256) void rmsnorm_kernel(
    const float* __restrict__ h, const float* __restrict__ w,
    unsigned short* __restrict__ ub) {
  int wave = threadIdx.x >> 6;
  int lane = threadIdx.x & 63;
  int tok = blockIdx.x * 4 + wave;
  const float* hp = h + (size_t)tok * DMODEL;
  float4 v = *(const float4*)&hp[lane * 4];
  float ss = v.x * v.x + v.y * v.y + v.z * v.z + v.w * v.w;
#pragma unroll
  for (int off = 32; off; off >>= 1) ss += __shfl_xor(ss, off, 64);
  float rs = rsqrtf(ss * (1.0f / 256.0f) + 1e-5f);
  float4 wv = *(const float4*)&w[lane * 4];
  ushort4 o;
  o.x = f2bf(v.x * rs * wv.x);
  o.y = f2bf(v.y * rs * wv.y);
  o.z = f2bf(v.z * rs * wv.z);
  o.w = f2bf(v.w * rs * wv.w);
  *(ushort4*)&ub[(size_t)tok * DMODEL + lane * 4] = o;
}

__global__ __launch_bounds__(256) void cast_weights_kernel(
    const float* __restrict__ wa, const float* __restrict__ wo,
    unsigned short* __restrict__ dA, unsigned short* __restrict__ dO) {
  int i = (blockIdx.x * 256 + threadIdx.x) * 4;
  if (i < WA_ELEMS) {
    float4 v = *(const float4*)&wa[i];
    ushort4 o = {f2bf(v.x), f2bf(v.y), f2bf(v.z), f2bf(v.w)};
    *(ushort4*)&dA[i] = o;
  } else {
    int j = i - WA_ELEMS;
    float4 v = *(const float4*)&wo[j];
    ushort4 o = {f2bf(v.x), f2bf(v.y), f2bf(v.z), f2bf(v.w)};
    *(ushort4*)&dO[j] = o;
  }
}

__global__ __launch_bounds__(256) void gemm_bf16_split(
    const unsigned short* __restrict__ A, const unsigned short* __restrict__ Bw,
    float* __restrict__ C, unsigned short* __restrict__ Cz, int M, int N, int K) {
  __shared__ unsigned short As[128 * 32];
  __shared__ unsigned short Bs[128 * 32];
  int tid = threadIdx.x;
  int wave = tid >> 6;
  int lane = tid & 63;
  int wm = (wave & 1) * 64;
  int wn = (wave >> 1) * 64;
  int m0 = blockIdx.y * 128;
  int n0 = blockIdx.x * 128;
  int mlane = lane & 15;
  int quad = lane >> 4;
  floatx4 acc[4][4] = {};
  for (int k0 = 0; k0 < K; k0 += 32) {
#pragma unroll
    for (int i = 0; i < 2; i++) {
      int off = i * 4096 + wave * 1024 + lane * 16;
      int row = off >> 6, col = off & 63;
      load_lds16((const char*)A + ((size_t)(m0 + row) * K + k0) * 2 + col,
                 (char*)As + i * 4096 + wave * 1024);
    }
#pragma unroll
    for (int i = 0; i < 2; i++) {
      int off = i * 4096 + wave * 1024 + lane * 16;
      int row = off >> 6, col = off & 63;
      load_lds16((const char*)Bw + ((size_t)(n0 + row) * K + k0) * 2 + col,
                 (char*)Bs + i * 4096 + wave * 1024);
    }
    __syncthreads();
    short8 af[4], bf[4];
#pragma unroll
    for (int i = 0; i < 4; i++)
      af[i] = *(const short8*)((const char*)As + (wm + i * 16 + mlane) * 64 + quad * 16);
#pragma unroll
    for (int j = 0; j < 4; j++)
      bf[j] = *(const short8*)((const char*)Bs + (wn + j * 16 + mlane) * 64 + quad * 16);
#pragma unroll
    for (int i = 0; i < 4; i++)
#pragma unroll
      for (int j = 0; j < 4; j++)
        acc[i][j] = __builtin_amdgcn_mfma_f32_16x16x32_bf16(af[i], bf[j], acc[i][j], 0, 0, 0);
    __syncthreads();
  }
#pragma unroll
  for (int i = 0; i < 4; i++) {
#pragma unroll
    for (int j = 0; j < 4; j++) {
      int n = n0 + wn + j * 16 + mlane;
#pragma unroll
      for (int r = 0; r < 4; r++) {
        int m = m0 + wm + i * 16 + quad * 4 + r;
        float v = acc[i][j][r];
        if (n < DINNER) C[(size_t)m * DINNER + n] = v;
        else Cz[(size_t)m * DINNER + (n - DINNER)] = f2bf(v);
      }
    }
  }
}

__global__ __launch_bounds__(256) void gemm_bf16_n64(
    const unsigned short* __restrict__ A, const unsigned short* __restrict__ Bw,
    float* __restrict__ C, int M, int N, int K) {
  __shared__ unsigned short As[128 * 32];
  __shared__ unsigned short Bs[64 * 32];
  int tid = threadIdx.x;
  int wave = tid >> 6;
  int lane = tid & 63;
  int wm = wave * 32;
  int m0 = blockIdx.y * 128;
  int n0 = blockIdx.x * 64;
  int mlane = lane & 15;
  int quad = lane >> 4;
  floatx4 acc[2][4] = {};
  for (int k0 = 0; k0 < K; k0 += 32) {
#pragma unroll
    for (int i = 0; i < 2; i++) {
      int off = i * 4096 + wave * 1024 + lane * 16;
      int row = off >> 6, col = off & 63;
      load_lds16((const char*)A + ((size_t)(m0 + row) * K + k0) * 2 + col,
                 (char*)As + i * 4096 + wave * 1024);
    }
    {
      int off = wave * 1024 + lane * 16;
      int row = off >> 6, col = off & 63;
      load_lds16((const char*)Bw + ((size_t)(n0 + row) * K + k0) * 2 + col,
                 (char*)Bs + wave * 1024);
    }
    __syncthreads();
    short8 af[2], bf[4];
#pragma unroll
    for (int i = 0; i < 2; i++)
      af[i] = *(const short8*)((const char*)As + (wm + i * 16 + mlane) * 64 + quad * 16);
#pragma unroll
    for (int j = 0; j < 4; j++)
      bf[j] = *(const short8*)((const char*)Bs + (j * 16 + mlane) * 64 + quad * 16);
#pragma unroll
    for (int i = 0; i < 2; i++)
#pragma unroll
      for (int j = 0; j < 4; j++)
        acc[i][j] = __builtin_amdgcn_mfma_f32_16x16x32_bf16(af[i], bf[j], acc[i][j], 0, 0, 0);
    __syncthreads();
  }
#pragma unroll
  for (int i = 0; i < 2; i++) {
#pragma unroll
    for (int j = 0; j < 4; j++) {
      int n = n0 + j * 16 + mlane;
#pragma unroll
      for (int r = 0; r < 4; r++) {
        int m = m0 + wm + i * 16 + quad * 4 + r;
        float* p = &C[(size_t)m * N + n];
        *p = acc[i][j][r] + *p;
      }
    }
  }
}

__global__ __launch_bounds__(256) void gemm_bf16a32(
    const unsigned short* __restrict__ A, const float* __restrict__ Bw,
    float* __restrict__ C, int M, int N, int K) {
  __shared__ float As[32][32];
  __shared__ float Bs[32][64];
  int tid = threadIdx.x;
  int m0 = blockIdx.y * 32;
  int tx = tid & 15;
  int ty = tid >> 4;
  float acc[2][4] = {};
  for (int k0 = 0; k0 < K; k0 += 32) {
    {
      int r = tid >> 3;
      int c = (tid & 7) * 4;
      ushort4 a = *(const ushort4*)&A[(size_t)(m0 + r) * K + k0 + c];
      As[c + 0][r] = bf2f(a.x);
      As[c + 1][r] = bf2f(a.y);
      As[c + 2][r] = bf2f(a.z);
      As[c + 3][r] = bf2f(a.w);
    }
    {
      int rb = tid >> 2;
      int cb = (tid & 3) * 8;
#pragma unroll
      for (int i = 0; i < 2; i++) {
        int col = cb + i * 4;
        float4 v = make_float4(0.f, 0.f, 0.f, 0.f);
        if (rb < N) v = *(const float4*)&Bw[(size_t)rb * K + k0 + col];
        Bs[col + 0][rb] = v.x;
        Bs[col + 1][rb] = v.y;
        Bs[col + 2][rb] = v.z;
        Bs[col + 3][rb] = v.w;
      }
    }
    __syncthreads();
#pragma unroll
    for (int kk = 0; kk < 32; kk++) {
      float av[2];
#pragma unroll
      for (int i = 0; i < 2; i++) av[i] = As[kk][ty * 2 + i];
      float4 b = *(const float4*)&Bs[kk][tx * 4];
      float bv[4] = {b.x, b.y, b.z, b.w};
#pragma unroll
      for (int i = 0; i < 2; i++)
#pragma unroll
        for (int j = 0; j < 4; j++) acc[i][j] = fmaf(av[i], bv[j], acc[i][j]);
    }
    __syncthreads();
  }
  int n = tx * 4;
  if (n < N) {
#pragma unroll
    for (int i = 0; i < 2; i++) {
      int m = m0 + ty * 2 + i;
      float4 v = {acc[i][0], acc[i][1], acc[i][2], acc[i][3]};
      *(float4*)&C[(size_t)m * N + n] = v;
    }
  }
}

__global__ __launch_bounds__(256) void conv_silu_kernel(
    const float* __restrict__ xc, const float* __restrict__ cw,
    const float* __restrict__ cb, unsigned short* __restrict__ xs) {
  int idx = blockIdx.x * 256 + threadIdx.x;
  int c4 = (idx & 127) * 4;
  int rest = idx >> 7;
  int strip = rest & 255;
  int b = rest >> 8;
  int t0 = strip * 8;
  float wch[4][4];
#pragma unroll
  for (int c = 0; c < 4; c++) {
    float4 w = *(const float4*)&cw[(c4 + c) * DCONV];
    wch[c][0] = w.x; wch[c][1] = w.y; wch[c][2] = w.z; wch[c][3] = w.w;
  }
  float4 bias = *(const float4*)&cb[c4];
  const float* xp = xc + ((size_t)b * WW) * DINNER + c4;
  float4 xm3 = make_float4(0, 0, 0, 0), xm2 = xm3, xm1 = xm3;
  if (t0 >= 3) xm3 = *(const float4*)&xp[(size_t)(t0 - 3) * DINNER];
  if (t0 >= 2) xm2 = *(const float4*)&xp[(size_t)(t0 - 2) * DINNER];
  if (t0 >= 1) xm1 = *(const float4*)&xp[(size_t)(t0 - 1) * DINNER];
  unsigned short* op = xs + ((size_t)b * WW) * DINNER + c4;
#pragma unroll
  for (int t = t0; t < t0 + 8; t++) {
    float4 xcur = *(const float4*)&xp[(size_t)t * DINNER];
    float a0 = bias.x, a1 = bias.y, a2 = bias.z, a3 = bias.w;
    a0 = fmaf(xm3.x, wch[0][0], fmaf(xm2.x, wch[0][1], fmaf(xm1.x, wch[0][2], fmaf(xcur.x, wch[0][3], a0))));
    a1 = fmaf(xm3.y, wch[1][0], fmaf(xm2.y, wch[1][1], fmaf(xm1.y, wch[1][2], fmaf(xcur.y, wch[1][3], a1))));
    a2 = fmaf(xm3.z, wch[2][0], fmaf(xm2.z, wch[2][1], fmaf(xm1.z, wch[2][2], fmaf(xcur.z, wch[2][3], a2))));
    a3 = fmaf(xm3.w, wch[3][0], fmaf(xm2.w, wch[3][1], fmaf(xm1.w, wch[3][2], fmaf(xcur.w, wch[3][3], a3))));
    ushort4 o;
    o.x = f2bf(a0 / (1.f + __expf(-a0)));
    o.y = f2bf(a1 / (1.f + __expf(-a1)));
    o.z = f2bf(a2 / (1.f + __expf(-a2)));
    o.w = f2bf(a3 / (1.f + __expf(-a3)));
    *(ushort4*)&op[(size_t)t * DINNER] = o;
    xm3 = xm2; xm2 = xm1; xm1 = xcur;
  }
}

__global__ __launch_bounds__(256) void scan_phase1(
    const float* __restrict__ dbc, const unsigned short* __restrict__ xs,
    const float* __restrict__ dtw, const float* __restrict__ dtb,
    const float* __restrict__ A_log,
    float* __restrict__ Pfin, float* __restrict__ Hfin) {
  int blk = blockIdx.x;
  int dblk = blk & 1;
  int bc = blk >> 1;
  int c = bc & (CHUNKS - 1);
  int b = bc >> 6;
  int d = dblk * 256 + threadIdx.x;
  float A[16], wt[16];
#pragma unroll
  for (int j = 0; j < 4; j++) {
    float4 v = *(const float4*)&A_log[d * DSTATE + j * 4];
    A[4 * j + 0] = -__expf(v.x);
    A[4 * j + 1] = -__expf(v.y);
    A[4 * j + 2] = -__expf(v.z);
    A[4 * j + 3] = -__expf(v.w);
    float4 q = *(const float4*)&dtw[d * DTRANK + j * 4];
    wt[4 * j + 0] = q.x; wt[4 * j + 1] = q.y;
    wt[4 * j + 2] = q.z; wt[4 * j + 3] = q.w;
  }
  float bias = dtb[d];
  float h[16], P[16];
#pragma unroll
  for (int s = 0; s < 16; s++) { h[s] = 0.f; P[s] = 1.f; }
  int t0 = c * CLEN;
  const unsigned short* up_ = xs + ((size_t)(b * WW + t0)) * DINNER + d;
  const float* bcp = dbc + ((size_t)(b * WW + t0)) * 48;
#pragma unroll 4
  for (int t = 0; t < CLEN; t++) {
    float uv = bf2f(up_[(size_t)t * DINNER]);
    float dt16[16], Bv[16];
#pragma unroll
    for (int j = 0; j < 4; j++) {
      float4 q = *(const float4*)&bcp[t * 48 + j * 4];
      dt16[4 * j + 0] = q.x; dt16[4 * j + 1] = q.y;
      dt16[4 * j + 2] = q.z; dt16[4 * j + 3] = q.w;
      float4 r = *(const float4*)&bcp[t * 48 + DTRANK + j * 4];
      Bv[4 * j + 0] = r.x; Bv[4 * j + 1] = r.y;
      Bv[4 * j + 2] = r.z; Bv[4 * j + 3] = r.w;
    }
    float s0 = bias;
#pragma unroll
    for (int r = 0; r < 16; r++) s0 = fmaf(dt16[r], wt[r], s0);
    float dv = fmaxf(s0, 0.f) + __logf(1.f + __expf(-fabsf(s0)));
    float du = dv * uv;
#pragma unroll
    for (int s = 0; s < 16; s++) {
      float e = __expf(dv * A[s]);
      P[s] *= e;
      h[s] = fmaf(e, h[s], du * Bv[s]);
    }
  }
  size_t o = ((size_t)(b * DINNER + d) * CHUNKS + c) * DSTATE;
#pragma unroll
  for (int j = 0; j < 4; j++) {
    float4 pv = {P[4 * j], P[4 * j + 1], P[4 * j + 2], P[4 * j + 3]};
    float4 hv = {h[4 * j], h[4 * j + 1], h[4 * j + 2], h[4 * j + 3]};
    *(float4*)&Pfin[o + 4 * j] = pv;
    *(float4*)&Hfin[o + 4 * j] = hv;
  }
}

__global__ __launch_bounds__(256) void scan_phase2(
    float* __restrict__ Pfin, const float* __restrict__ Hfin) {
  int idx = blockIdx.x * 256 + threadIdx.x;
  int s = idx & 15;
  int g = idx >> 4;
  float h = 0.f;
#pragma unroll
  for (int c = 0; c < CHUNKS; c++) {
    size_t o = ((size_t)g * CHUNKS + c) * DSTATE + s;
    float P = Pfin[o];
    float f = Hfin[o];
    Pfin[o] = h;
    h = fmaf(P, h, f);
  }
}

__global__ __launch_bounds__(256) void scan_phase3(
    const float* __restrict__ dbc, const unsigned short* __restrict__ xs,
    const unsigned short* __restrict__ zb,
    const float* __restrict__ dtw, const float* __restrict__ dtb,
    const float* __restrict__ A_log, const float* __restrict__ Dp,
    const float* __restrict__ Hin, unsigned short* __restrict__ yb) {
  int blk = blockIdx.x;
  int dblk = blk & 1;
  int bc = blk >> 1;
  int c = bc & (CHUNKS - 1);
  int b = bc >> 6;
  int d = dblk * 256 + threadIdx.x;
  float A[16], wt[16];
#pragma unroll
  for (int j = 0; j < 4; j++) {
    float4 v = *(const float4*)&A_log[d * DSTATE + j * 4];
    A[4 * j + 0] = -__expf(v.x);
    A[4 * j + 1] = -__expf(v.y);
    A[4 * j + 2] = -__expf(v.z);
    A[4 * j + 3] = -__expf(v.w);
    float4 q = *(const float4*)&dtw[d * DTRANK + j * 4];
    wt[4 * j + 0] = q.x; wt[4 * j + 1] = q.y;
    wt[4 * j + 2] = q.z; wt[4 * j + 3] = q.w;
  }
  float bias = dtb[d];
  float Dv = Dp[d];
  float h[16];
  size_t o = ((size_t)(b * DINNER + d) * CHUNKS + c) * DSTATE;
#pragma unroll
  for (int j = 0; j < 4; j++) {
    float4 hv = *(const float4*)&Hin[o + 4 * j];
    h[4 * j + 0] = hv.x; h[4 * j + 1] = hv.y;
    h[4 * j + 2] = hv.z; h[4 * j + 3] = hv.w;
  }
  int t0 = c * CLEN;
  const unsigned short* up_ = xs + ((size_t)(b * WW + t0)) * DINNER + d;
  const float* bcp = dbc + ((size_t)(b * WW + t0)) * 48;
  const unsigned short* zp = zb + ((size_t)(b * WW + t0)) * DINNER + d;
  unsigned short* yp = yb + ((size_t)(b * WW + t0)) * DINNER + d;
#pragma unroll 4
  for (int t = 0; t < CLEN; t++) {
    float uv = bf2f(up_[(size_t)t * DINNER]);
    float zv = bf2f(zp[(size_t)t * DINNER]);
    float dt16[16], Bv[16], Cv[16];
#pragma unroll
    for (int j = 0; j < 4; j++) {
      float4 q = *(const float4*)&bcp[t * 48 + j * 4];
      dt16[4 * j + 0] = q.x; dt16[4 * j + 1] = q.y;
      dt16[4 * j + 2] = q.z; dt16[4 * j + 3] = q.w;
      float4 r = *(const float4*)&bcp[t * 48 + DTRANK + j * 4];
      Bv[4 * j + 0] = r.x; Bv[4 * j + 1] = r.y;
      Bv[4 * j + 2] = r.z; Bv[4 * j + 3] = r.w;
      float4 u2 = *(const float4*)&bcp[t * 48 + DTRANK + DSTATE + j * 4];
      Cv[4 * j + 0] = u2.x; Cv[4 * j + 1] = u2.y;
      Cv[4 * j + 2] = u2.z; Cv[4 * j + 3] = u2.w;
    }
    float s0 = bias;
#pragma unroll
    for (int r = 0; r < 16; r++) s0 = fmaf(dt16[r], wt[r], s0);
    float dv = fmaxf(s0, 0.f) + __logf(1.f + __expf(-fabsf(s0)));
    float du = dv * uv;
    float p = 0.f;
#pragma unroll
    for (int s = 0; s < 16; s++) {
      float e = __expf(dv * A[s]);
      h[s] = fmaf(e, h[s], du * Bv[s]);
      p = fmaf(h[s], Cv[s], p);
    }
    float yv = fmaf(uv, Dv, p);
    yv *= zv / (1.f + __expf(-zv));
    yp[(size_t)t * DINNER] = f2bf(yv);
  }
}

// ---------------------------------------------------------------------------
extern "C" void kernel_launch(void* const* d_in, const int* in_sizes, int n_in,
                              void* d_out, int out_size, void* d_ws, size_t ws_size,
                              hipStream_t stream) {
  const float* x = (const float*)d_in[0];
  const float* emb_w = (const float*)d_in[1];
  const float* emb_b = (const float*)d_in[2];
  const float* in_proj_w = (const float*)d_in[3];
  const float* conv_w = (const float*)d_in[4];
  const float* conv_b = (const float*)d_in[5];
  const float* x_proj_w = (const float*)d_in[6];
  const float* dt_proj_w = (const float*)d_in[7];
  const float* dt_proj_b = (const float*)d_in[8];
  const float* A_log = (const float*)d_in[9];
  const float* Dp = (const float*)d_in[10];
  const float* out_proj_w = (const float*)d_in[11];
  const float* norm_w = (const float*)d_in[12];
  float* hout = (float*)d_out;
  float* wsf = (float*)d_ws;

  const size_t M1 = 1024 * 1024;
  unsigned short* ub = (unsigned short*)wsf;
  float* xc = wsf + 1 * M1;
  unsigned short* zb = (unsigned short*)(wsf + 5 * M1);
  unsigned short* xs = (unsigned short*)(wsf + 7 * M1);
  float* dbc = wsf + 9 * M1;
  float* pf = wsf + 9 * M1 + 524288;
  float* hf = pf + 2 * M1;
  unsigned short* ybb = (unsigned short*)(hf + 2 * M1);
  unsigned short* wA_all = (unsigned short*)(wsf + 15 * M1 + 524288);
  unsigned short* wO_all = wA_all + (size_t)WA_ELEMS;

  // Pick cooperative grid size by queried co-residency (deterministic).
  int maxBlocksPerCU = 0;
  hipError_t oerr = hipOccupancyMaxActiveBlocksPerMultiprocessor(
      &maxBlocksPerCU, mamba_mega, 256, 0);
  int grid = (oerr == hipSuccess && maxBlocksPerCU >= 2) ? 512 : 256;

  void* kargs[] = {
      (void*)&x, (void*)&emb_w, (void*)&emb_b, (void*)&in_proj_w,
      (void*)&conv_w, (void*)&conv_b, (void*)&x_proj_w, (void*)&dt_proj_w,
      (void*)&dt_proj_b, (void*)&A_log, (void*)&Dp, (void*)&out_proj_w,
      (void*)&norm_w, (void*)&hout, (void*)&wsf};
  hipError_t lerr = hipLaunchCooperativeKernel(
      reinterpret_cast<void*>(&mamba_mega), dim3(grid), dim3(256), kargs, 0,
      stream);
  if (lerr == hipSuccess) return;
  (void)hipGetLastError();  // clear error state; fall back to R8 pipeline

  cast_weights_kernel<<<(WA_ELEMS + WO_ELEMS) / 1024, 256, 0, stream>>>(
      in_proj_w, out_proj_w, wA_all, wO_all);
  for (int l = 0; l < NLAYERS; l++) {
    const unsigned short* wA = wA_all + (size_t)l * 2 * DINNER * DMODEL;
    const unsigned short* wO = wO_all + (size_t)l * DMODEL * DINNER;
    if (l == 0)
      embed_rms_kernel<<<2048, 256, 0, stream>>>(x, emb_w, emb_b, norm_w, hout, ub);
    else
      rmsnorm_kernel<<<2048, 256, 0, stream>>>(hout, norm_w + l * DMODEL, ub);
    gemm_bf16_split<<<dim3(8, 64), 256, 0, stream>>>(
        ub, wA, xc, zb, TOK, 2 * DINNER, DMODEL);
    conv_silu_kernel<<<512, 256, 0, stream>>>(
        xc, conv_w + (size_t)l * DINNER * DCONV, conv_b + (size_t)l * DINNER, xs);
    gemm_bf16a32<<<dim3(1, 256), 256, 0, stream>>>(
        xs, x_proj_w + (size_t)l * 48 * DINNER, dbc, TOK, 48, DINNER);
    scan_phase1<<<512, 256, 0, stream>>>(
        dbc, xs, dt_proj_w + (size_t)l * DINNER * DTRANK,
        dt_proj_b + (size_t)l * DINNER, A_log + (size_t)l * DINNER * DSTATE,
        pf, hf);
    scan_phase2<<<128, 256, 0, stream>>>(pf, hf);
    scan_phase3<<<512, 256, 0, stream>>>(
        dbc, xs, zb, dt_proj_w + (size_t)l * DINNER * DTRANK,
        dt_proj_b + (size_t)l * DINNER, A_log + (size_t)l * DINNER * DSTATE,
        Dp + (size_t)l * DINNER, pf, ybb);
    gemm_bf16_n64<<<dim3(4, 64), 256, 0, stream>>>(
        ybb, wO, hout, TOK, DMODEL, DINNER);
  }
}

// Round 12
// 349.421 us; speedup vs baseline: 2.7814x; 2.7814x over previous
//
#include <hip/hip_runtime.h>
#include <hip/hip_bf16.h>
#include <math.h>

// Problem constants
#define BB 4
#define WW 2048
#define TOK (BB * WW)        // 8192
#define DMODEL 256
#define DINNER 512
#define DSTATE 16
#define DTRANK 16
#define DCONV 4
#define NLAYERS 2
#define CHUNKS 64
#define CLEN (WW / CHUNKS)   // 32
#define WA_ELEMS (NLAYERS * 2 * DINNER * DMODEL)   // 1048576
#define WO_ELEMS (NLAYERS * DMODEL * DINNER)       // 524288

typedef __attribute__((ext_vector_type(8))) short short8;
typedef __attribute__((ext_vector_type(4))) float floatx4;

static __device__ __forceinline__ unsigned short f2bf(float f) {
  __hip_bfloat16 b = __float2bfloat16(f);
  return *(unsigned short*)&b;
}
static __device__ __forceinline__ float bf2f(unsigned short u) {
  union { unsigned int i; float f; } x;
  x.i = ((unsigned int)u) << 16;
  return x.f;
}
static __device__ __forceinline__ float4 ld_bf4(const unsigned short* p) {
  ushort4 u = *(const ushort4*)p;
  float4 v;
  v.x = bf2f(u.x); v.y = bf2f(u.y); v.z = bf2f(u.z); v.w = bf2f(u.w);
  return v;
}
static __device__ __forceinline__ void load_lds16(const void* g, void* l) {
  __builtin_amdgcn_global_load_lds(
      (const __attribute__((address_space(1))) unsigned int*)g,
      (__attribute__((address_space(3))) unsigned int*)l, 16, 0, 0);
}

// NOTE (R10 learning): grid.sync() costs ~60us on MI355X (device quiesce
// across 8 non-coherent XCDs) — kernel launches (~5us in graph replay) are
// cheaper.  Multi-kernel pipeline is the right structure here.
// NOTE (R11 learning): merged cast/embed prologue coincided with an HSA
// abort; reverted to R8's separate proven kernels to isolate variables.

// ---------------------------------------------------------------------------
// Fused embed + RMSNorm (layer 0) — R8-proven
// ---------------------------------------------------------------------------
__global__ __launch_bounds__(256) void embed_rms_kernel(
    const float* __restrict__ x, const float* __restrict__ ew,
    const float* __restrict__ eb, const float* __restrict__ nw,
    float* __restrict__ h, unsigned short* __restrict__ ub) {
  int wave = threadIdx.x >> 6;
  int lane = threadIdx.x & 63;
  int tok = blockIdx.x * 4 + wave;
  int d4 = lane * 4;
  float xv = x[tok];
  float4 w = *(const float4*)&ew[d4];
  float4 b = *(const float4*)&eb[d4];
  float4 e;
  e.x = xv * w.x + b.x;
  e.y = xv * w.y + b.y;
  e.z = xv * w.z + b.z;
  e.w = xv * w.w + b.w;
  *(float4*)&h[(size_t)tok * DMODEL + d4] = e;
  float ss = e.x * e.x + e.y * e.y + e.z * e.z + e.w * e.w;
#pragma unroll
  for (int off = 32; off; off >>= 1) ss += __shfl_xor(ss, off, 64);
  float rs = rsqrtf(ss * (1.0f / 256.0f) + 1e-5f);
  float4 nv = *(const float4*)&nw[d4];
  ushort4 o;
  o.x = f2bf(e.x * rs * nv.x);
  o.y = f2bf(e.y * rs * nv.y);
  o.z = f2bf(e.z * rs * nv.z);
  o.w = f2bf(e.w * rs * nv.w);
  *(ushort4*)&ub[(size_t)tok * DMODEL + d4] = o;
}

// ---------------------------------------------------------------------------
// RMSNorm (layer >=1) — R8-proven
// ---------------------------------------------------------------------------
__global__ __launch_bounds__(256) void rmsnorm_kernel(
    const float* __restrict__ h, const float* __restrict__ w,
    unsigned short* __restrict__ ub) {
  int wave = threadIdx.x >> 6;
  int lane = threadIdx.x & 63;
  int tok = blockIdx.x * 4 + wave;
  const float* hp = h + (size_t)tok * DMODEL;
  float4 v = *(const float4*)&hp[lane * 4];
  float ss = v.x * v.x + v.y * v.y + v.z * v.z + v.w * v.w;
#pragma unroll
  for (int off = 32; off; off >>= 1) ss += __shfl_xor(ss, off, 64);
  float rs = rsqrtf(ss * (1.0f / 256.0f) + 1e-5f);
  float4 wv = *(const float4*)&w[lane * 4];
  ushort4 o;
  o.x = f2bf(v.x * rs * wv.x);
  o.y = f2bf(v.y * rs * wv.y);
  o.z = f2bf(v.z * rs * wv.z);
  o.w = f2bf(v.w * rs * wv.w);
  *(ushort4*)&ub[(size_t)tok * DMODEL + lane * 4] = o;
}

// ---------------------------------------------------------------------------
// Combined weight cast — R8-proven
// ---------------------------------------------------------------------------
__global__ __launch_bounds__(256) void cast_weights_kernel(
    const float* __restrict__ wa, const float* __restrict__ wo,
    unsigned short* __restrict__ dA, unsigned short* __restrict__ dO) {
  int i = (blockIdx.x * 256 + threadIdx.x) * 4;
  if (i < WA_ELEMS) {
    float4 v = *(const float4*)&wa[i];
    ushort4 o = {f2bf(v.x), f2bf(v.y), f2bf(v.z), f2bf(v.w)};
    *(ushort4*)&dA[i] = o;
  } else {
    int j = i - WA_ELEMS;
    float4 v = *(const float4*)&wo[j];
    ushort4 o = {f2bf(v.x), f2bf(v.y), f2bf(v.z), f2bf(v.w)};
    *(ushort4*)&dO[j] = o;
  }
}

// ---------------------------------------------------------------------------
// in_proj bf16 MFMA GEMM: 128x128 tile, BK=32; split epilogue, both halves
// bf16: cols <512 -> xcb, cols >=512 -> zb.  (R12 change vs R8: xc bf16)
// ---------------------------------------------------------------------------
__global__ __launch_bounds__(256) void gemm_bf16_split(
    const unsigned short* __restrict__ A, const unsigned short* __restrict__ Bw,
    unsigned short* __restrict__ xcb, unsigned short* __restrict__ zb,
    int M, int N, int K) {
  __shared__ unsigned short As[128 * 32];
  __shared__ unsigned short Bs[128 * 32];
  int tid = threadIdx.x;
  int wave = tid >> 6;
  int lane = tid & 63;
  int wm = (wave & 1) * 64;
  int wn = (wave >> 1) * 64;
  int m0 = blockIdx.y * 128;
  int n0 = blockIdx.x * 128;
  int mlane = lane & 15;
  int quad = lane >> 4;
  floatx4 acc[4][4] = {};
  for (int k0 = 0; k0 < K; k0 += 32) {
#pragma unroll
    for (int i = 0; i < 2; i++) {
      int off = i * 4096 + wave * 1024 + lane * 16;
      int row = off >> 6, col = off & 63;
      load_lds16((const char*)A + ((size_t)(m0 + row) * K + k0) * 2 + col,
                 (char*)As + i * 4096 + wave * 1024);
    }
#pragma unroll
    for (int i = 0; i < 2; i++) {
      int off = i * 4096 + wave * 1024 + lane * 16;
      int row = off >> 6, col = off & 63;
      load_lds16((const char*)Bw + ((size_t)(n0 + row) * K + k0) * 2 + col,
                 (char*)Bs + i * 4096 + wave * 1024);
    }
    __syncthreads();
    short8 af[4], bf[4];
#pragma unroll
    for (int i = 0; i < 4; i++)
      af[i] = *(const short8*)((const char*)As + (wm + i * 16 + mlane) * 64 + quad * 16);
#pragma unroll
    for (int j = 0; j < 4; j++)
      bf[j] = *(const short8*)((const char*)Bs + (wn + j * 16 + mlane) * 64 + quad * 16);
#pragma unroll
    for (int i = 0; i < 4; i++)
#pragma unroll
      for (int j = 0; j < 4; j++)
        acc[i][j] = __builtin_amdgcn_mfma_f32_16x16x32_bf16(af[i], bf[j], acc[i][j], 0, 0, 0);
    __syncthreads();
  }
#pragma unroll
  for (int i = 0; i < 4; i++) {
#pragma unroll
    for (int j = 0; j < 4; j++) {
      int n = n0 + wn + j * 16 + mlane;
#pragma unroll
      for (int r = 0; r < 4; r++) {
        int m = m0 + wm + i * 16 + quad * 4 + r;
        unsigned short bv = f2bf(acc[i][j][r]);
        if (n < DINNER) xcb[(size_t)m * DINNER + n] = bv;
        else zb[(size_t)m * DINNER + (n - DINNER)] = bv;
      }
    }
  }
}

// ---------------------------------------------------------------------------
// out_proj bf16 MFMA GEMM, 128x64 tile, C += A*B^T — R8-proven
// ---------------------------------------------------------------------------
__global__ __launch_bounds__(256) void gemm_bf16_n64(
    const unsigned short* __restrict__ A, const unsigned short* __restrict__ Bw,
    float* __restrict__ C, int M, int N, int K) {
  __shared__ unsigned short As[128 * 32];
  __shared__ unsigned short Bs[64 * 32];
  int tid = threadIdx.x;
  int wave = tid >> 6;
  int lane = tid & 63;
  int wm = wave * 32;
  int m0 = blockIdx.y * 128;
  int n0 = blockIdx.x * 64;
  int mlane = lane & 15;
  int quad = lane >> 4;
  floatx4 acc[2][4] = {};
  for (int k0 = 0; k0 < K; k0 += 32) {
#pragma unroll
    for (int i = 0; i < 2; i++) {
      int off = i * 4096 + wave * 1024 + lane * 16;
      int row = off >> 6, col = off & 63;
      load_lds16((const char*)A + ((size_t)(m0 + row) * K + k0) * 2 + col,
                 (char*)As + i * 4096 + wave * 1024);
    }
    {
      int off = wave * 1024 + lane * 16;
      int row = off >> 6, col = off & 63;
      load_lds16((const char*)Bw + ((size_t)(n0 + row) * K + k0) * 2 + col,
                 (char*)Bs + wave * 1024);
    }
    __syncthreads();
    short8 af[2], bf[4];
#pragma unroll
    for (int i = 0; i < 2; i++)
      af[i] = *(const short8*)((const char*)As + (wm + i * 16 + mlane) * 64 + quad * 16);
#pragma unroll
    for (int j = 0; j < 4; j++)
      bf[j] = *(const short8*)((const char*)Bs + (j * 16 + mlane) * 64 + quad * 16);
#pragma unroll
    for (int i = 0; i < 2; i++)
#pragma unroll
      for (int j = 0; j < 4; j++)
        acc[i][j] = __builtin_amdgcn_mfma_f32_16x16x32_bf16(af[i], bf[j], acc[i][j], 0, 0, 0);
    __syncthreads();
  }
#pragma unroll
  for (int i = 0; i < 2; i++) {
#pragma unroll
    for (int j = 0; j < 4; j++) {
      int n = n0 + j * 16 + mlane;
#pragma unroll
      for (int r = 0; r < 4; r++) {
        int m = m0 + wm + i * 16 + quad * 4 + r;
        float* p = &C[(size_t)m * N + n];
        *p = acc[i][j][r] + *p;
      }
    }
  }
}

// ---------------------------------------------------------------------------
// x_proj GEMM: C[M,48] = A_bf16[M,512] * B_fp32[48,512]^T.  BM=32 — R8-proven
// ---------------------------------------------------------------------------
__global__ __launch_bounds__(256) void gemm_bf16a32(
    const unsigned short* __restrict__ A, const float* __restrict__ Bw,
    float* __restrict__ C, int M, int N, int K) {
  __shared__ float As[32][32];
  __shared__ float Bs[32][64];
  int tid = threadIdx.x;
  int m0 = blockIdx.y * 32;
  int tx = tid & 15;
  int ty = tid >> 4;
  float acc[2][4] = {};
  for (int k0 = 0; k0 < K; k0 += 32) {
    {
      int r = tid >> 3;
      int c = (tid & 7) * 4;
      ushort4 a = *(const ushort4*)&A[(size_t)(m0 + r) * K + k0 + c];
      As[c + 0][r] = bf2f(a.x);
      As[c + 1][r] = bf2f(a.y);
      As[c + 2][r] = bf2f(a.z);
      As[c + 3][r] = bf2f(a.w);
    }
    {
      int rb = tid >> 2;
      int cb = (tid & 3) * 8;
#pragma unroll
      for (int i = 0; i < 2; i++) {
        int col = cb + i * 4;
        float4 v = make_float4(0.f, 0.f, 0.f, 0.f);
        if (rb < N) v = *(const float4*)&Bw[(size_t)rb * K + k0 + col];
        Bs[col + 0][rb] = v.x;
        Bs[col + 1][rb] = v.y;
        Bs[col + 2][rb] = v.z;
        Bs[col + 3][rb] = v.w;
      }
    }
    __syncthreads();
#pragma unroll
    for (int kk = 0; kk < 32; kk++) {
      float av[2];
#pragma unroll
      for (int i = 0; i < 2; i++) av[i] = As[kk][ty * 2 + i];
      float4 b = *(const float4*)&Bs[kk][tx * 4];
      float bv[4] = {b.x, b.y, b.z, b.w};
#pragma unroll
      for (int i = 0; i < 2; i++)
#pragma unroll
        for (int j = 0; j < 4; j++) acc[i][j] = fmaf(av[i], bv[j], acc[i][j]);
    }
    __syncthreads();
  }
  int n = tx * 4;
  if (n < N) {
#pragma unroll
    for (int i = 0; i < 2; i++) {
      int m = m0 + ty * 2 + i;
      float4 v = {acc[i][0], acc[i][1], acc[i][2], acc[i][3]};
      *(float4*)&C[(size_t)m * N + n] = v;
    }
  }
}

// ---------------------------------------------------------------------------
// Causal depthwise conv + SiLU; xcb bf16 in, xs bf16 out.  Sliding window,
// 4 channels x 8-token strip, 512 blocks.
// ---------------------------------------------------------------------------
__global__ __launch_bounds__(256) void conv_silu_kernel(
    const unsigned short* __restrict__ xcb, const float* __restrict__ cw,
    const float* __restrict__ cb, unsigned short* __restrict__ xs) {
  int idx = blockIdx.x * 256 + threadIdx.x;    // 131072
  int c4 = (idx & 127) * 4;
  int rest = idx >> 7;
  int strip = rest & 255;
  int b = rest >> 8;
  int t0 = strip * 8;
  float wch[4][4];
#pragma unroll
  for (int c = 0; c < 4; c++) {
    float4 w = *(const float4*)&cw[(c4 + c) * DCONV];
    wch[c][0] = w.x; wch[c][1] = w.y; wch[c][2] = w.z; wch[c][3] = w.w;
  }
  float4 bias = *(const float4*)&cb[c4];
  const unsigned short* xp = xcb + ((size_t)b * WW) * DINNER + c4;
  float4 xm3 = make_float4(0, 0, 0, 0), xm2 = xm3, xm1 = xm3;
  if (t0 >= 3) xm3 = ld_bf4(&xp[(size_t)(t0 - 3) * DINNER]);
  if (t0 >= 2) xm2 = ld_bf4(&xp[(size_t)(t0 - 2) * DINNER]);
  if (t0 >= 1) xm1 = ld_bf4(&xp[(size_t)(t0 - 1) * DINNER]);
  unsigned short* op = xs + ((size_t)b * WW) * DINNER + c4;
#pragma unroll
  for (int t = t0; t < t0 + 8; t++) {
    float4 xcur = ld_bf4(&xp[(size_t)t * DINNER]);
    float a0 = bias.x, a1 = bias.y, a2 = bias.z, a3 = bias.w;
    a0 = fmaf(xm3.x, wch[0][0], fmaf(xm2.x, wch[0][1], fmaf(xm1.x, wch[0][2], fmaf(xcur.x, wch[0][3], a0))));
    a1 = fmaf(xm3.y, wch[1][0], fmaf(xm2.y, wch[1][1], fmaf(xm1.y, wch[1][2], fmaf(xcur.y, wch[1][3], a1))));
    a2 = fmaf(xm3.z, wch[2][0], fmaf(xm2.z, wch[2][1], fmaf(xm1.z, wch[2][2], fmaf(xcur.z, wch[2][3], a2))));
    a3 = fmaf(xm3.w, wch[3][0], fmaf(xm2.w, wch[3][1], fmaf(xm1.w, wch[3][2], fmaf(xcur.w, wch[3][3], a3))));
    ushort4 o;
    o.x = f2bf(a0 / (1.f + __expf(-a0)));
    o.y = f2bf(a1 / (1.f + __expf(-a1)));
    o.z = f2bf(a2 / (1.f + __expf(-a2)));
    o.w = f2bf(a3 / (1.f + __expf(-a3)));
    *(ushort4*)&op[(size_t)t * DINNER] = o;
    xm3 = xm2; xm2 = xm1; xm1 = xcur;
  }
}

// ---------------------------------------------------------------------------
// Chunked selective scan with fused dt-projection+softplus — R8-proven
// ---------------------------------------------------------------------------
__global__ __launch_bounds__(256) void scan_phase1(
    const float* __restrict__ dbc, const unsigned short* __restrict__ xs,
    const float* __restrict__ dtw, const float* __restrict__ dtb,
    const float* __restrict__ A_log,
    float* __restrict__ Pfin, float* __restrict__ Hfin) {
  int blk = blockIdx.x;            // (b*CHUNKS + c)*2 + dblk
  int dblk = blk & 1;
  int bc = blk >> 1;
  int c = bc & (CHUNKS - 1);
  int b = bc >> 6;
  int d = dblk * 256 + threadIdx.x;
  float A[16], wt[16];
#pragma unroll
  for (int j = 0; j < 4; j++) {
    float4 v = *(const float4*)&A_log[d * DSTATE + j * 4];
    A[4 * j + 0] = -__expf(v.x);
    A[4 * j + 1] = -__expf(v.y);
    A[4 * j + 2] = -__expf(v.z);
    A[4 * j + 3] = -__expf(v.w);
    float4 q = *(const float4*)&dtw[d * DTRANK + j * 4];
    wt[4 * j + 0] = q.x; wt[4 * j + 1] = q.y;
    wt[4 * j + 2] = q.z; wt[4 * j + 3] = q.w;
  }
  float bias = dtb[d];
  float h[16], P[16];
#pragma unroll
  for (int s = 0; s < 16; s++) { h[s] = 0.f; P[s] = 1.f; }
  int t0 = c * CLEN;
  const unsigned short* up_ = xs + ((size_t)(b * WW + t0)) * DINNER + d;
  const float* bcp = dbc + ((size_t)(b * WW + t0)) * 48;
#pragma unroll 4
  for (int t = 0; t < CLEN; t++) {
    float uv = bf2f(up_[(size_t)t * DINNER]);
    float dt16[16], Bv[16];
#pragma unroll
    for (int j = 0; j < 4; j++) {
      float4 q = *(const float4*)&bcp[t * 48 + j * 4];
      dt16[4 * j + 0] = q.x; dt16[4 * j + 1] = q.y;
      dt16[4 * j + 2] = q.z; dt16[4 * j + 3] = q.w;
      float4 r = *(const float4*)&bcp[t * 48 + DTRANK + j * 4];
      Bv[4 * j + 0] = r.x; Bv[4 * j + 1] = r.y;
      Bv[4 * j + 2] = r.z; Bv[4 * j + 3] = r.w;
    }
    float s0 = bias;
#pragma unroll
    for (int r = 0; r < 16; r++) s0 = fmaf(dt16[r], wt[r], s0);
    float dv = fmaxf(s0, 0.f) + __logf(1.f + __expf(-fabsf(s0)));
    float du = dv * uv;
#pragma unroll
    for (int s = 0; s < 16; s++) {
      float e = __expf(dv * A[s]);
      P[s] *= e;
      h[s] = fmaf(e, h[s], du * Bv[s]);
    }
  }
  size_t o = ((size_t)(b * DINNER + d) * CHUNKS + c) * DSTATE;
#pragma unroll
  for (int j = 0; j < 4; j++) {
    float4 pv = {P[4 * j], P[4 * j + 1], P[4 * j + 2], P[4 * j + 3]};
    float4 hv = {h[4 * j], h[4 * j + 1], h[4 * j + 2], h[4 * j + 3]};
    *(float4*)&Pfin[o + 4 * j] = pv;
    *(float4*)&Hfin[o + 4 * j] = hv;
  }
}

__global__ __launch_bounds__(256) void scan_phase2(
    float* __restrict__ Pfin, const float* __restrict__ Hfin) {
  int idx = blockIdx.x * 256 + threadIdx.x;  // 32768 = g*16+s
  int s = idx & 15;
  int g = idx >> 4;
  float h = 0.f;
#pragma unroll
  for (int c = 0; c < CHUNKS; c++) {
    size_t o = ((size_t)g * CHUNKS + c) * DSTATE + s;
    float P = Pfin[o];
    float f = Hfin[o];
    Pfin[o] = h;             // carry-in for chunk c
    h = fmaf(P, h, f);
  }
}

__global__ __launch_bounds__(256) void scan_phase3(
    const float* __restrict__ dbc, const unsigned short* __restrict__ xs,
    const unsigned short* __restrict__ zb,
    const float* __restrict__ dtw, const float* __restrict__ dtb,
    const float* __restrict__ A_log, const float* __restrict__ Dp,
    const float* __restrict__ Hin, unsigned short* __restrict__ yb) {
  int blk = blockIdx.x;
  int dblk = blk & 1;
  int bc = blk >> 1;
  int c = bc & (CHUNKS - 1);
  int b = bc >> 6;
  int d = dblk * 256 + threadIdx.x;
  float A[16], wt[16];
#pragma unroll
  for (int j = 0; j < 4; j++) {
    float4 v = *(const float4*)&A_log[d * DSTATE + j * 4];
    A[4 * j + 0] = -__expf(v.x);
    A[4 * j + 1] = -__expf(v.y);
    A[4 * j + 2] = -__expf(v.z);
    A[4 * j + 3] = -__expf(v.w);
    float4 q = *(const float4*)&dtw[d * DTRANK + j * 4];
    wt[4 * j + 0] = q.x; wt[4 * j + 1] = q.y;
    wt[4 * j + 2] = q.z; wt[4 * j + 3] = q.w;
  }
  float bias = dtb[d];
  float Dv = Dp[d];
  float h[16];
  size_t o = ((size_t)(b * DINNER + d) * CHUNKS + c) * DSTATE;
#pragma unroll
  for (int j = 0; j < 4; j++) {
    float4 hv = *(const float4*)&Hin[o + 4 * j];
    h[4 * j + 0] = hv.x; h[4 * j + 1] = hv.y;
    h[4 * j + 2] = hv.z; h[4 * j + 3] = hv.w;
  }
  int t0 = c * CLEN;
  const unsigned short* up_ = xs + ((size_t)(b * WW + t0)) * DINNER + d;
  const float* bcp = dbc + ((size_t)(b * WW + t0)) * 48;
  const unsigned short* zp = zb + ((size_t)(b * WW + t0)) * DINNER + d;
  unsigned short* yp = yb + ((size_t)(b * WW + t0)) * DINNER + d;
#pragma unroll 4
  for (int t = 0; t < CLEN; t++) {
    float uv = bf2f(up_[(size_t)t * DINNER]);
    float zv = bf2f(zp[(size_t)t * DINNER]);
    float dt16[16], Bv[16], Cv[16];
#pragma unroll
    for (int j = 0; j < 4; j++) {
      float4 q = *(const float4*)&bcp[t * 48 + j * 4];
      dt16[4 * j + 0] = q.x; dt16[4 * j + 1] = q.y;
      dt16[4 * j + 2] = q.z; dt16[4 * j + 3] = q.w;
      float4 r = *(const float4*)&bcp[t * 48 + DTRANK + j * 4];
      Bv[4 * j + 0] = r.x; Bv[4 * j + 1] = r.y;
      Bv[4 * j + 2] = r.z; Bv[4 * j + 3] = r.w;
      float4 u2 = *(const float4*)&bcp[t * 48 + DTRANK + DSTATE + j * 4];
      Cv[4 * j + 0] = u2.x; Cv[4 * j + 1] = u2.y;
      Cv[4 * j + 2] = u2.z; Cv[4 * j + 3] = u2.w;
    }
    float s0 = bias;
#pragma unroll
    for (int r = 0; r < 16; r++) s0 = fmaf(dt16[r], wt[r], s0);
    float dv = fmaxf(s0, 0.f) + __logf(1.f + __expf(-fabsf(s0)));
    float du = dv * uv;
    float p = 0.f;
#pragma unroll
    for (int s = 0; s < 16; s++) {
      float e = __expf(dv * A[s]);
      h[s] = fmaf(e, h[s], du * Bv[s]);
      p = fmaf(h[s], Cv[s], p);
    }
    float yv = fmaf(uv, Dv, p);
    yv *= zv / (1.f + __expf(-zv));
    yp[(size_t)t * DINNER] = f2bf(yv);
  }
}

// ---------------------------------------------------------------------------
extern "C" void kernel_launch(void* const* d_in, const int* in_sizes, int n_in,
                              void* d_out, int out_size, void* d_ws, size_t ws_size,
                              hipStream_t stream) {
  const float* x = (const float*)d_in[0];
  const float* emb_w = (const float*)d_in[1];
  const float* emb_b = (const float*)d_in[2];
  const float* in_proj_w = (const float*)d_in[3];
  const float* conv_w = (const float*)d_in[4];
  const float* conv_b = (const float*)d_in[5];
  const float* x_proj_w = (const float*)d_in[6];
  const float* dt_proj_w = (const float*)d_in[7];
  const float* dt_proj_b = (const float*)d_in[8];
  const float* A_log = (const float*)d_in[9];
  const float* Dp = (const float*)d_in[10];
  const float* out_proj_w = (const float*)d_in[11];
  const float* norm_w = (const float*)d_in[12];
  float* hout = (float*)d_out;
  float* ws = (float*)d_ws;

  // R8-proven region map (float-equivalent offsets); only change: the old
  // xc fp32 region [1M,5M) now holds xcb bf16 in [1M,3M) ([3M,5M) unused).
  //   [0,1M)       : ub bf16 (TOKxDMODEL = 2M bf16)
  //   [1M,3M)      : xcb bf16 (TOKxDINNER = 4M bf16)
  //   [5M,7M)      : zb bf16
  //   [7M,9M)      : xs bf16
  //   [9M,9.375M)  : dbc fp32 (TOKx48)
  //   [9.5M,11.5M) : pf fp32
  //   [11.5M,13.5M): hf fp32
  //   [13.5M,15.5M): ybb bf16
  //   [15.5M,16M)  : wA bf16 (1048576)
  //   [16M,16.25M) : wO bf16 (524288)
  const size_t M1 = 1024 * 1024;
  unsigned short* ub = (unsigned short*)ws;
  unsigned short* xcb = (unsigned short*)(ws + 1 * M1);
  unsigned short* zb = (unsigned short*)(ws + 5 * M1);
  unsigned short* xs = (unsigned short*)(ws + 7 * M1);
  float* dbc = ws + 9 * M1;
  float* pf = ws + 9 * M1 + 524288;
  float* hf = pf + 2 * M1;
  unsigned short* ybb = (unsigned short*)(hf + 2 * M1);
  unsigned short* wA_all = (unsigned short*)(ws + 15 * M1 + 524288);
  unsigned short* wO_all = wA_all + (size_t)WA_ELEMS;

  cast_weights_kernel<<<(WA_ELEMS + WO_ELEMS) / 1024, 256, 0, stream>>>(
      in_proj_w, out_proj_w, wA_all, wO_all);

  for (int l = 0; l < NLAYERS; l++) {
    const unsigned short* wA = wA_all + (size_t)l * 2 * DINNER * DMODEL;
    const unsigned short* wO = wO_all + (size_t)l * DMODEL * DINNER;

    if (l == 0)
      embed_rms_kernel<<<2048, 256, 0, stream>>>(x, emb_w, emb_b, norm_w, hout, ub);
    else
      rmsnorm_kernel<<<2048, 256, 0, stream>>>(hout, norm_w + l * DMODEL, ub);

    // in_proj: split epilogue -> xcb bf16 + zb bf16
    gemm_bf16_split<<<dim3(8, 64), 256, 0, stream>>>(
        ub, wA, xcb, zb, TOK, 2 * DINNER, DMODEL);
    // conv + silu (sliding window, bf16 in/out)
    conv_silu_kernel<<<512, 256, 0, stream>>>(
        xcb, conv_w + (size_t)l * DINNER * DCONV, conv_b + (size_t)l * DINNER, xs);
    // x_proj: (8192,48) = xs_bf16 @ W^T (fp32 weights/accum)
    gemm_bf16a32<<<dim3(1, 256), 256, 0, stream>>>(
        xs, x_proj_w + (size_t)l * 48 * DINNER, dbc, TOK, 48, DINNER);
    // Chunked scan with fused dt-projection
    scan_phase1<<<BB * CHUNKS * 2, 256, 0, stream>>>(
        dbc, xs, dt_proj_w + (size_t)l * DINNER * DTRANK,
        dt_proj_b + (size_t)l * DINNER, A_log + (size_t)l * DINNER * DSTATE,
        pf, hf);
    scan_phase2<<<128, 256, 0, stream>>>(pf, hf);
    scan_phase3<<<BB * CHUNKS * 2, 256, 0, stream>>>(
        dbc, xs, zb, dt_proj_w + (size_t)l * DINNER * DTRANK,
        dt_proj_b + (size_t)l * DINNER, A_log + (size_t)l * DINNER * DSTATE,
        Dp + (size_t)l * DINNER, pf, ybb);
    // out_proj (+residual): h += ybb @ wO^T
    gemm_bf16_n64<<<dim3(4, 64), 256, 0, stream>>>(
        ybb, wO, hout, TOK, DMODEL, DINNER);
  }
}

// Round 13
// 316.810 us; speedup vs baseline: 3.0677x; 1.1029x over previous
//
#include <hip/hip_runtime.h>
#include <hip/hip_bf16.h>
#include <math.h>

// Problem constants
#define BB 4
#define WW 2048
#define TOK (BB * WW)        // 8192
#define DMODEL 256
#define DINNER 512
#define DSTATE 16
#define DTRANK 16
#define DCONV 4
#define NLAYERS 2
#define CHUNKS 128
#define CLEN (WW / CHUNKS)   // 16
#define WA_ELEMS (NLAYERS * 2 * DINNER * DMODEL)   // 1048576
#define WO_ELEMS (NLAYERS * DMODEL * DINNER)       // 524288
#define WX_ROWS 64
#define WX_ELEMS (NLAYERS * WX_ROWS * DINNER)      // 65536 (48 real + 16 zero rows)

typedef __attribute__((ext_vector_type(8))) short short8;
typedef __attribute__((ext_vector_type(4))) float floatx4;

static __device__ __forceinline__ unsigned short f2bf(float f) {
  __hip_bfloat16 b = __float2bfloat16(f);
  return *(unsigned short*)&b;
}
static __device__ __forceinline__ float bf2f(unsigned short u) {
  union { unsigned int i; float f; } x;
  x.i = ((unsigned int)u) << 16;
  return x.f;
}
static __device__ __forceinline__ float4 ld_bf4(const unsigned short* p) {
  ushort4 u = *(const ushort4*)p;
  float4 v;
  v.x = bf2f(u.x); v.y = bf2f(u.y); v.z = bf2f(u.z); v.w = bf2f(u.w);
  return v;
}
static __device__ __forceinline__ void load_lds16(const void* g, void* l) {
  __builtin_amdgcn_global_load_lds(
      (const __attribute__((address_space(1))) unsigned int*)g,
      (__attribute__((address_space(3))) unsigned int*)l, 16, 0, 0);
}

// NOTE (R10): grid.sync() ~60us on MI355X; kernel launches ~5us in graph
// replay. Multi-kernel pipeline is correct structure.  (R11): merged
// cast/embed prologue coincided with HSA abort; keep kernels separate.

// ---------------------------------------------------------------------------
// Fused embed + RMSNorm (layer 0) — R8-proven
// ---------------------------------------------------------------------------
__global__ __launch_bounds__(256) void embed_rms_kernel(
    const float* __restrict__ x, const float* __restrict__ ew,
    const float* __restrict__ eb, const float* __restrict__ nw,
    float* __restrict__ h, unsigned short* __restrict__ ub) {
  int wave = threadIdx.x >> 6;
  int lane = threadIdx.x & 63;
  int tok = blockIdx.x * 4 + wave;
  int d4 = lane * 4;
  float xv = x[tok];
  float4 w = *(const float4*)&ew[d4];
  float4 b = *(const float4*)&eb[d4];
  float4 e;
  e.x = xv * w.x + b.x;
  e.y = xv * w.y + b.y;
  e.z = xv * w.z + b.z;
  e.w = xv * w.w + b.w;
  *(float4*)&h[(size_t)tok * DMODEL + d4] = e;
  float ss = e.x * e.x + e.y * e.y + e.z * e.z + e.w * e.w;
#pragma unroll
  for (int off = 32; off; off >>= 1) ss += __shfl_xor(ss, off, 64);
  float rs = rsqrtf(ss * (1.0f / 256.0f) + 1e-5f);
  float4 nv = *(const float4*)&nw[d4];
  ushort4 o;
  o.x = f2bf(e.x * rs * nv.x);
  o.y = f2bf(e.y * rs * nv.y);
  o.z = f2bf(e.z * rs * nv.z);
  o.w = f2bf(e.w * rs * nv.w);
  *(ushort4*)&ub[(size_t)tok * DMODEL + d4] = o;
}

// ---------------------------------------------------------------------------
// RMSNorm (layer >=1) — R8-proven
// ---------------------------------------------------------------------------
__global__ __launch_bounds__(256) void rmsnorm_kernel(
    const float* __restrict__ h, const float* __restrict__ w,
    unsigned short* __restrict__ ub) {
  int wave = threadIdx.x >> 6;
  int lane = threadIdx.x & 63;
  int tok = blockIdx.x * 4 + wave;
  const float* hp = h + (size_t)tok * DMODEL;
  float4 v = *(const float4*)&hp[lane * 4];
  float ss = v.x * v.x + v.y * v.y + v.z * v.z + v.w * v.w;
#pragma unroll
  for (int off = 32; off; off >>= 1) ss += __shfl_xor(ss, off, 64);
  float rs = rsqrtf(ss * (1.0f / 256.0f) + 1e-5f);
  float4 wv = *(const float4*)&w[lane * 4];
  ushort4 o;
  o.x = f2bf(v.x * rs * wv.x);
  o.y = f2bf(v.y * rs * wv.y);
  o.z = f2bf(v.z * rs * wv.z);
  o.w = f2bf(v.w * rs * wv.w);
  *(ushort4*)&ub[(size_t)tok * DMODEL + lane * 4] = o;
}

// ---------------------------------------------------------------------------
// Combined weight cast: in_proj + out_proj + x_proj (zero-padded to 64 rows)
// 1600 blocks x 256 threads x 4 elems.
// ---------------------------------------------------------------------------
__global__ __launch_bounds__(256) void cast_weights_kernel(
    const float* __restrict__ wa, const float* __restrict__ wo,
    const float* __restrict__ wx,
    unsigned short* __restrict__ dA, unsigned short* __restrict__ dO,
    unsigned short* __restrict__ dX) {
  int i = (blockIdx.x * 256 + threadIdx.x) * 4;
  if (i < WA_ELEMS) {
    float4 v = *(const float4*)&wa[i];
    ushort4 o = {f2bf(v.x), f2bf(v.y), f2bf(v.z), f2bf(v.w)};
    *(ushort4*)&dA[i] = o;
  } else if (i < WA_ELEMS + WO_ELEMS) {
    int j = i - WA_ELEMS;
    float4 v = *(const float4*)&wo[j];
    ushort4 o = {f2bf(v.x), f2bf(v.y), f2bf(v.z), f2bf(v.w)};
    *(ushort4*)&dO[j] = o;
  } else {
    int j = i - WA_ELEMS - WO_ELEMS;           // [0, WX_ELEMS)
    int l = j >> 15;                           // / (64*512)
    int rem = j & 32767;
    int row = rem >> 9;                        // / 512
    int k = rem & 511;
    ushort4 o = {0, 0, 0, 0};
    if (row < 48) {
      float4 v = *(const float4*)&wx[((size_t)l * 48 + row) * DINNER + k];
      o.x = f2bf(v.x); o.y = f2bf(v.y); o.z = f2bf(v.z); o.w = f2bf(v.w);
    }
    *(ushort4*)&dX[j] = o;
  }
}

// ---------------------------------------------------------------------------
// in_proj bf16 MFMA GEMM: 128x128 tile, BK=32; split epilogue both bf16.
// ---------------------------------------------------------------------------
__global__ __launch_bounds__(256) void gemm_bf16_split(
    const unsigned short* __restrict__ A, const unsigned short* __restrict__ Bw,
    unsigned short* __restrict__ xcb, unsigned short* __restrict__ zb,
    int M, int N, int K) {
  __shared__ unsigned short As[128 * 32];
  __shared__ unsigned short Bs[128 * 32];
  int tid = threadIdx.x;
  int wave = tid >> 6;
  int lane = tid & 63;
  int wm = (wave & 1) * 64;
  int wn = (wave >> 1) * 64;
  int m0 = blockIdx.y * 128;
  int n0 = blockIdx.x * 128;
  int mlane = lane & 15;
  int quad = lane >> 4;
  floatx4 acc[4][4] = {};
  for (int k0 = 0; k0 < K; k0 += 32) {
#pragma unroll
    for (int i = 0; i < 2; i++) {
      int off = i * 4096 + wave * 1024 + lane * 16;
      int row = off >> 6, col = off & 63;
      load_lds16((const char*)A + ((size_t)(m0 + row) * K + k0) * 2 + col,
                 (char*)As + i * 4096 + wave * 1024);
    }
#pragma unroll
    for (int i = 0; i < 2; i++) {
      int off = i * 4096 + wave * 1024 + lane * 16;
      int row = off >> 6, col = off & 63;
      load_lds16((const char*)Bw + ((size_t)(n0 + row) * K + k0) * 2 + col,
                 (char*)Bs + i * 4096 + wave * 1024);
    }
    __syncthreads();
    short8 af[4], bf[4];
#pragma unroll
    for (int i = 0; i < 4; i++)
      af[i] = *(const short8*)((const char*)As + (wm + i * 16 + mlane) * 64 + quad * 16);
#pragma unroll
    for (int j = 0; j < 4; j++)
      bf[j] = *(const short8*)((const char*)Bs + (wn + j * 16 + mlane) * 64 + quad * 16);
#pragma unroll
    for (int i = 0; i < 4; i++)
#pragma unroll
      for (int j = 0; j < 4; j++)
        acc[i][j] = __builtin_amdgcn_mfma_f32_16x16x32_bf16(af[i], bf[j], acc[i][j], 0, 0, 0);
    __syncthreads();
  }
#pragma unroll
  for (int i = 0; i < 4; i++) {
#pragma unroll
    for (int j = 0; j < 4; j++) {
      int n = n0 + wn + j * 16 + mlane;
#pragma unroll
      for (int r = 0; r < 4; r++) {
        int m = m0 + wm + i * 16 + quad * 4 + r;
        unsigned short bv = f2bf(acc[i][j][r]);
        if (n < DINNER) xcb[(size_t)m * DINNER + n] = bv;
        else zb[(size_t)m * DINNER + (n - DINNER)] = bv;
      }
    }
  }
}

// ---------------------------------------------------------------------------
// x_proj bf16 MFMA GEMM: 128x64 tile, B padded to 64 rows (rows 48..63 zero),
// C[M,48] overwrite with n<48 mask.  Grid (1, M/128) = 64 blocks.
// ---------------------------------------------------------------------------
__global__ __launch_bounds__(256) void gemm_xproj(
    const unsigned short* __restrict__ A, const unsigned short* __restrict__ Bw,
    float* __restrict__ C, int M, int K) {
  __shared__ unsigned short As[128 * 32];
  __shared__ unsigned short Bs[64 * 32];
  int tid = threadIdx.x;
  int wave = tid >> 6;
  int lane = tid & 63;
  int wm = wave * 32;
  int m0 = blockIdx.y * 128;
  int mlane = lane & 15;
  int quad = lane >> 4;
  floatx4 acc[2][4] = {};
  for (int k0 = 0; k0 < K; k0 += 32) {
#pragma unroll
    for (int i = 0; i < 2; i++) {
      int off = i * 4096 + wave * 1024 + lane * 16;
      int row = off >> 6, col = off & 63;
      load_lds16((const char*)A + ((size_t)(m0 + row) * K + k0) * 2 + col,
                 (char*)As + i * 4096 + wave * 1024);
    }
    {
      int off = wave * 1024 + lane * 16;
      int row = off >> 6, col = off & 63;
      load_lds16((const char*)Bw + ((size_t)row * K + k0) * 2 + col,
                 (char*)Bs + wave * 1024);
    }
    __syncthreads();
    short8 af[2], bf[4];
#pragma unroll
    for (int i = 0; i < 2; i++)
      af[i] = *(const short8*)((const char*)As + (wm + i * 16 + mlane) * 64 + quad * 16);
#pragma unroll
    for (int j = 0; j < 4; j++)
      bf[j] = *(const short8*)((const char*)Bs + (j * 16 + mlane) * 64 + quad * 16);
#pragma unroll
    for (int i = 0; i < 2; i++)
#pragma unroll
      for (int j = 0; j < 4; j++)
        acc[i][j] = __builtin_amdgcn_mfma_f32_16x16x32_bf16(af[i], bf[j], acc[i][j], 0, 0, 0);
    __syncthreads();
  }
#pragma unroll
  for (int i = 0; i < 2; i++) {
#pragma unroll
    for (int j = 0; j < 3; j++) {            // n in [0,48): j=3 tile discarded
      int n = j * 16 + mlane;
#pragma unroll
      for (int r = 0; r < 4; r++) {
        int m = m0 + wm + i * 16 + quad * 4 + r;
        C[(size_t)m * 48 + n] = acc[i][j][r];
      }
    }
  }
}

// ---------------------------------------------------------------------------
// out_proj bf16 MFMA GEMM, 128x32 tile (512 blocks), C += A*B^T.
// Structure ran correct inside R10's mega-kernel (S7).
// ---------------------------------------------------------------------------
__global__ __launch_bounds__(256) void gemm_out32(
    const unsigned short* __restrict__ A, const unsigned short* __restrict__ Bw,
    float* __restrict__ C, int M, int N, int K) {
  __shared__ unsigned short As[128 * 32];   // 8 KB
  __shared__ unsigned short Bs[32 * 32];    // 2 KB
  int tid = threadIdx.x;
  int wave = tid >> 6;
  int lane = tid & 63;
  int m0 = blockIdx.y * 128;
  int n0 = blockIdx.x * 32;
  int mlane = lane & 15;
  int quad = lane >> 4;
  floatx4 acc[2][2] = {};
  for (int k0 = 0; k0 < K; k0 += 32) {
#pragma unroll
    for (int i = 0; i < 2; i++) {
      int off = i * 4096 + wave * 1024 + lane * 16;
      int row = off >> 6, col = off & 63;
      load_lds16((const char*)A + ((size_t)(m0 + row) * K + k0) * 2 + col,
                 (char*)As + i * 4096 + wave * 1024);
    }
    if (wave < 2) {
      int off = wave * 1024 + lane * 16;
      int row = off >> 6, col = off & 63;
      load_lds16((const char*)Bw + ((size_t)(n0 + row) * K + k0) * 2 + col,
                 (char*)Bs + wave * 1024);
    }
    __syncthreads();
    short8 af[2], bf[2];
#pragma unroll
    for (int i = 0; i < 2; i++)
      af[i] = *(const short8*)((const char*)As + (wave * 32 + i * 16 + mlane) * 64 + quad * 16);
#pragma unroll
    for (int j = 0; j < 2; j++)
      bf[j] = *(const short8*)((const char*)Bs + (j * 16 + mlane) * 64 + quad * 16);
#pragma unroll
    for (int i = 0; i < 2; i++)
#pragma unroll
      for (int j = 0; j < 2; j++)
        acc[i][j] = __builtin_amdgcn_mfma_f32_16x16x32_bf16(af[i], bf[j], acc[i][j], 0, 0, 0);
    __syncthreads();
  }
#pragma unroll
  for (int i = 0; i < 2; i++) {
#pragma unroll
    for (int j = 0; j < 2; j++) {
      int n = n0 + j * 16 + mlane;
#pragma unroll
      for (int r = 0; r < 4; r++) {
        int m = m0 + wave * 32 + i * 16 + quad * 4 + r;
        float* p = &C[(size_t)m * N + n];
        *p = acc[i][j][r] + *p;
      }
    }
  }
}

// ---------------------------------------------------------------------------
// Causal depthwise conv + SiLU; bf16 in/out.  4 channels x 8-token strip.
// ---------------------------------------------------------------------------
__global__ __launch_bounds__(256) void conv_silu_kernel(
    const unsigned short* __restrict__ xcb, const float* __restrict__ cw,
    const float* __restrict__ cb, unsigned short* __restrict__ xs) {
  int idx = blockIdx.x * 256 + threadIdx.x;    // 131072
  int c4 = (idx & 127) * 4;
  int rest = idx >> 7;
  int strip = rest & 255;
  int b = rest >> 8;
  int t0 = strip * 8;
  float wch[4][4];
#pragma unroll
  for (int c = 0; c < 4; c++) {
    float4 w = *(const float4*)&cw[(c4 + c) * DCONV];
    wch[c][0] = w.x; wch[c][1] = w.y; wch[c][2] = w.z; wch[c][3] = w.w;
  }
  float4 bias = *(const float4*)&cb[c4];
  const unsigned short* xp = xcb + ((size_t)b * WW) * DINNER + c4;
  float4 xm3 = make_float4(0, 0, 0, 0), xm2 = xm3, xm1 = xm3;
  if (t0 >= 3) xm3 = ld_bf4(&xp[(size_t)(t0 - 3) * DINNER]);
  if (t0 >= 2) xm2 = ld_bf4(&xp[(size_t)(t0 - 2) * DINNER]);
  if (t0 >= 1) xm1 = ld_bf4(&xp[(size_t)(t0 - 1) * DINNER]);
  unsigned short* op = xs + ((size_t)b * WW) * DINNER + c4;
#pragma unroll
  for (int t = t0; t < t0 + 8; t++) {
    float4 xcur = ld_bf4(&xp[(size_t)t * DINNER]);
    float a0 = bias.x, a1 = bias.y, a2 = bias.z, a3 = bias.w;
    a0 = fmaf(xm3.x, wch[0][0], fmaf(xm2.x, wch[0][1], fmaf(xm1.x, wch[0][2], fmaf(xcur.x, wch[0][3], a0))));
    a1 = fmaf(xm3.y, wch[1][0], fmaf(xm2.y, wch[1][1], fmaf(xm1.y, wch[1][2], fmaf(xcur.y, wch[1][3], a1))));
    a2 = fmaf(xm3.z, wch[2][0], fmaf(xm2.z, wch[2][1], fmaf(xm1.z, wch[2][2], fmaf(xcur.z, wch[2][3], a2))));
    a3 = fmaf(xm3.w, wch[3][0], fmaf(xm2.w, wch[3][1], fmaf(xm1.w, wch[3][2], fmaf(xcur.w, wch[3][3], a3))));
    ushort4 o;
    o.x = f2bf(a0 / (1.f + __expf(-a0)));
    o.y = f2bf(a1 / (1.f + __expf(-a1)));
    o.z = f2bf(a2 / (1.f + __expf(-a2)));
    o.w = f2bf(a3 / (1.f + __expf(-a3)));
    *(ushort4*)&op[(size_t)t * DINNER] = o;
    xm3 = xm2; xm2 = xm1; xm1 = xcur;
  }
}

// ---------------------------------------------------------------------------
// Chunked selective scan with fused dt-projection+softplus.  CHUNKS=128
// (CLEN=16) -> 1024 blocks = 4096 waves = 4/SIMD.
// ---------------------------------------------------------------------------
__global__ __launch_bounds__(256) void scan_phase1(
    const float* __restrict__ dbc, const unsigned short* __restrict__ xs,
    const float* __restrict__ dtw, const float* __restrict__ dtb,
    const float* __restrict__ A_log,
    float* __restrict__ Pfin, float* __restrict__ Hfin) {
  int blk = blockIdx.x;            // (b*CHUNKS + c)*2 + dblk
  int dblk = blk & 1;
  int bc = blk >> 1;
  int c = bc % CHUNKS;
  int b = bc / CHUNKS;
  int d = dblk * 256 + threadIdx.x;
  float A[16], wt[16];
#pragma unroll
  for (int j = 0; j < 4; j++) {
    float4 v = *(const float4*)&A_log[d * DSTATE + j * 4];
    A[4 * j + 0] = -__expf(v.x);
    A[4 * j + 1] = -__expf(v.y);
    A[4 * j + 2] = -__expf(v.z);
    A[4 * j + 3] = -__expf(v.w);
    float4 q = *(const float4*)&dtw[d * DTRANK + j * 4];
    wt[4 * j + 0] = q.x; wt[4 * j + 1] = q.y;
    wt[4 * j + 2] = q.z; wt[4 * j + 3] = q.w;
  }
  float bias = dtb[d];
  float h[16], P[16];
#pragma unroll
  for (int s = 0; s < 16; s++) { h[s] = 0.f; P[s] = 1.f; }
  int t0 = c * CLEN;
  const unsigned short* up_ = xs + ((size_t)(b * WW + t0)) * DINNER + d;
  const float* bcp = dbc + ((size_t)(b * WW + t0)) * 48;
#pragma unroll 4
  for (int t = 0; t < CLEN; t++) {
    float uv = bf2f(up_[(size_t)t * DINNER]);
    float dt16[16], Bv[16];
#pragma unroll
    for (int j = 0; j < 4; j++) {
      float4 q = *(const float4*)&bcp[t * 48 + j * 4];
      dt16[4 * j + 0] = q.x; dt16[4 * j + 1] = q.y;
      dt16[4 * j + 2] = q.z; dt16[4 * j + 3] = q.w;
      float4 r = *(const float4*)&bcp[t * 48 + DTRANK + j * 4];
      Bv[4 * j + 0] = r.x; Bv[4 * j + 1] = r.y;
      Bv[4 * j + 2] = r.z; Bv[4 * j + 3] = r.w;
    }
    float s0 = bias;
#pragma unroll
    for (int r = 0; r < 16; r++) s0 = fmaf(dt16[r], wt[r], s0);
    float dv = fmaxf(s0, 0.f) + __logf(1.f + __expf(-fabsf(s0)));
    float du = dv * uv;
#pragma unroll
    for (int s = 0; s < 16; s++) {
      float e = __expf(dv * A[s]);
      P[s] *= e;
      h[s] = fmaf(e, h[s], du * Bv[s]);
    }
  }
  size_t o = ((size_t)(b * DINNER + d) * CHUNKS + c) * DSTATE;
#pragma unroll
  for (int j = 0; j < 4; j++) {
    float4 pv = {P[4 * j], P[4 * j + 1], P[4 * j + 2], P[4 * j + 3]};
    float4 hv = {h[4 * j], h[4 * j + 1], h[4 * j + 2], h[4 * j + 3]};
    *(float4*)&Pfin[o + 4 * j] = pv;
    *(float4*)&Hfin[o + 4 * j] = hv;
  }
}

__global__ __launch_bounds__(256) void scan_phase2(
    float* __restrict__ Pfin, const float* __restrict__ Hfin) {
  int idx = blockIdx.x * 256 + threadIdx.x;  // 32768 = g*16+s
  int s = idx & 15;
  int g = idx >> 4;
  float h = 0.f;
#pragma unroll 8
  for (int c = 0; c < CHUNKS; c++) {
    size_t o = ((size_t)g * CHUNKS + c) * DSTATE + s;
    float P = Pfin[o];
    float f = Hfin[o];
    Pfin[o] = h;             // carry-in for chunk c
    h = fmaf(P, h, f);
  }
}

__global__ __launch_bounds__(256) void scan_phase3(
    const float* __restrict__ dbc, const unsigned short* __restrict__ xs,
    const unsigned short* __restrict__ zb,
    const float* __restrict__ dtw, const float* __restrict__ dtb,
    const float* __restrict__ A_log, const float* __restrict__ Dp,
    const float* __restrict__ Hin, unsigned short* __restrict__ yb) {
  int blk = blockIdx.x;
  int dblk = blk & 1;
  int bc = blk >> 1;
  int c = bc % CHUNKS;
  int b = bc / CHUNKS;
  int d = dblk * 256 + threadIdx.x;
  float A[16], wt[16];
#pragma unroll
  for (int j = 0; j < 4; j++) {
    float4 v = *(const float4*)&A_log[d * DSTATE + j * 4];
    A[4 * j + 0] = -__expf(v.x);
    A[4 * j + 1] = -__expf(v.y);
    A[4 * j + 2] = -__expf(v.z);
    A[4 * j + 3] = -__expf(v.w);
    float4 q = *(const float4*)&dtw[d * DTRANK + j * 4];
    wt[4 * j + 0] = q.x; wt[4 * j + 1] = q.y;
    wt[4 * j + 2] = q.z; wt[4 * j + 3] = q.w;
  }
  float bias = dtb[d];
  float Dv = Dp[d];
  float h[16];
  size_t o = ((size_t)(b * DINNER + d) * CHUNKS + c) * DSTATE;
#pragma unroll
  for (int j = 0; j < 4; j++) {
    float4 hv = *(const float4*)&Hin[o + 4 * j];
    h[4 * j + 0] = hv.x; h[4 * j + 1] = hv.y;
    h[4 * j + 2] = hv.z; h[4 * j + 3] = hv.w;
  }
  int t0 = c * CLEN;
  const unsigned short* up_ = xs + ((size_t)(b * WW + t0)) * DINNER + d;
  const float* bcp = dbc + ((size_t)(b * WW + t0)) * 48;
  const unsigned short* zp = zb + ((size_t)(b * WW + t0)) * DINNER + d;
  unsigned short* yp = yb + ((size_t)(b * WW + t0)) * DINNER + d;
#pragma unroll 4
  for (int t = 0; t < CLEN; t++) {
    float uv = bf2f(up_[(size_t)t * DINNER]);
    float zv = bf2f(zp[(size_t)t * DINNER]);
    float dt16[16], Bv[16], Cv[16];
#pragma unroll
    for (int j = 0; j < 4; j++) {
      float4 q = *(const float4*)&bcp[t * 48 + j * 4];
      dt16[4 * j + 0] = q.x; dt16[4 * j + 1] = q.y;
      dt16[4 * j + 2] = q.z; dt16[4 * j + 3] = q.w;
      float4 r = *(const float4*)&bcp[t * 48 + DTRANK + j * 4];
      Bv[4 * j + 0] = r.x; Bv[4 * j + 1] = r.y;
      Bv[4 * j + 2] = r.z; Bv[4 * j + 3] = r.w;
      float4 u2 = *(const float4*)&bcp[t * 48 + DTRANK + DSTATE + j * 4];
      Cv[4 * j + 0] = u2.x; Cv[4 * j + 1] = u2.y;
      Cv[4 * j + 2] = u2.z; Cv[4 * j + 3] = u2.w;
    }
    float s0 = bias;
#pragma unroll
    for (int r = 0; r < 16; r++) s0 = fmaf(dt16[r], wt[r], s0);
    float dv = fmaxf(s0, 0.f) + __logf(1.f + __expf(-fabsf(s0)));
    float du = dv * uv;
    float p = 0.f;
#pragma unroll
    for (int s = 0; s < 16; s++) {
      float e = __expf(dv * A[s]);
      h[s] = fmaf(e, h[s], du * Bv[s]);
      p = fmaf(h[s], Cv[s], p);
    }
    float yv = fmaf(uv, Dv, p);
    yv *= zv / (1.f + __expf(-zv));
    yp[(size_t)t * DINNER] = f2bf(yv);
  }
}

// ---------------------------------------------------------------------------
extern "C" void kernel_launch(void* const* d_in, const int* in_sizes, int n_in,
                              void* d_out, int out_size, void* d_ws, size_t ws_size,
                              hipStream_t stream) {
  const float* x = (const float*)d_in[0];
  const float* emb_w = (const float*)d_in[1];
  const float* emb_b = (const float*)d_in[2];
  const float* in_proj_w = (const float*)d_in[3];
  const float* conv_w = (const float*)d_in[4];
  const float* conv_b = (const float*)d_in[5];
  const float* x_proj_w = (const float*)d_in[6];
  const float* dt_proj_w = (const float*)d_in[7];
  const float* dt_proj_b = (const float*)d_in[8];
  const float* A_log = (const float*)d_in[9];
  const float* Dp = (const float*)d_in[10];
  const float* out_proj_w = (const float*)d_in[11];
  const float* norm_w = (const float*)d_in[12];
  float* hout = (float*)d_out;
  float* ws = (float*)d_ws;

  // Region map (float-equivalent offsets), ALL DISJOINT (~81 MB):
  //   [0,1M)       : ub bf16
  //   [1M,3M)      : xcb bf16
  //   [5M,7M)      : zb bf16
  //   [7M,9M)      : xs bf16
  //   [9M,9.375M)  : dbc fp32 (TOKx48)
  //   [9.5M,13.5M) : pf fp32 (4M: 2048 g x 128 c x 16 s)
  //   [13.5M,17.5M): hf fp32 (4M)
  //   [17.5M,19.5M): ybb bf16
  //   [19.5M,20M)  : wA bf16 (1048576)
  //   [20M,20.25M) : wO bf16 (524288)
  //   [20.25M,+32K): wX bf16 (65536, 64-row padded)
  const size_t M1 = 1024 * 1024;
  unsigned short* ub = (unsigned short*)ws;
  unsigned short* xcb = (unsigned short*)(ws + 1 * M1);
  unsigned short* zb = (unsigned short*)(ws + 5 * M1);
  unsigned short* xs = (unsigned short*)(ws + 7 * M1);
  float* dbc = ws + 9 * M1;
  float* pf = ws + 9 * M1 + 524288;
  float* hf = pf + 4 * M1;
  unsigned short* ybb = (unsigned short*)(hf + 4 * M1);
  unsigned short* wA_all = (unsigned short*)(ws + 19 * M1 + 524288);
  unsigned short* wO_all = wA_all + (size_t)WA_ELEMS;
  unsigned short* wX_all = wO_all + (size_t)WO_ELEMS;

  cast_weights_kernel<<<(WA_ELEMS + WO_ELEMS + WX_ELEMS) / 1024, 256, 0, stream>>>(
      in_proj_w, out_proj_w, x_proj_w, wA_all, wO_all, wX_all);

  for (int l = 0; l < NLAYERS; l++) {
    const unsigned short* wA = wA_all + (size_t)l * 2 * DINNER * DMODEL;
    const unsigned short* wO = wO_all + (size_t)l * DMODEL * DINNER;
    const unsigned short* wX = wX_all + (size_t)l * WX_ROWS * DINNER;

    if (l == 0)
      embed_rms_kernel<<<2048, 256, 0, stream>>>(x, emb_w, emb_b, norm_w, hout, ub);
    else
      rmsnorm_kernel<<<2048, 256, 0, stream>>>(hout, norm_w + l * DMODEL, ub);

    // in_proj: split epilogue -> xcb bf16 + zb bf16
    gemm_bf16_split<<<dim3(8, 64), 256, 0, stream>>>(
        ub, wA, xcb, zb, TOK, 2 * DINNER, DMODEL);
    // conv + silu (sliding window, bf16 in/out)
    conv_silu_kernel<<<512, 256, 0, stream>>>(
        xcb, conv_w + (size_t)l * DINNER * DCONV, conv_b + (size_t)l * DINNER, xs);
    // x_proj: (8192,48) = xs_bf16 @ wX^T  [MFMA, 64 blocks]
    gemm_xproj<<<dim3(1, 64), 256, 0, stream>>>(xs, wX, dbc, TOK, DINNER);
    // Chunked scan with fused dt-projection (1024 blocks each)
    scan_phase1<<<BB * CHUNKS * 2, 256, 0, stream>>>(
        dbc, xs, dt_proj_w + (size_t)l * DINNER * DTRANK,
        dt_proj_b + (size_t)l * DINNER, A_log + (size_t)l * DINNER * DSTATE,
        pf, hf);
    scan_phase2<<<128, 256, 0, stream>>>(pf, hf);
    scan_phase3<<<BB * CHUNKS * 2, 256, 0, stream>>>(
        dbc, xs, zb, dt_proj_w + (size_t)l * DINNER * DTRANK,
        dt_proj_b + (size_t)l * DINNER, A_log + (size_t)l * DINNER * DSTATE,
        Dp + (size_t)l * DINNER, pf, ybb);
    // out_proj (+residual): h += ybb @ wO^T  (128x32 tile -> 512 blocks)
    gemm_out32<<<dim3(8, 64), 256, 0, stream>>>(
        ybb, wO, hout, TOK, DMODEL, DINNER);
  }
}